// Round 1
// baseline (491.809 us; speedup 1.0000x reference)
//
#include <hip/hip_runtime.h>
#include <hip/hip_bf16.h>
#include <cstdint>

// Problem constants
#define NHEAD 16
#define HDIM  64
#define WINL  512
#define STRW  256
#define GTOK  64
#define BATCH 2
#define SEQ   4096
#define HID   1024

using bf16x8 = __attribute__((ext_vector_type(8))) short;
using f32x4  = __attribute__((ext_vector_type(4))) float;
typedef unsigned short u16;
typedef unsigned int   u32;

__device__ __forceinline__ u16 f2bf(float f) {
  u32 u = __builtin_bit_cast(u32, f);
  u += 0x7fffu + ((u >> 16) & 1u);           // RNE
  return (u16)(u >> 16);
}
__device__ __forceinline__ float bf2f(u16 s) {
  return __builtin_bit_cast(float, (u32)s << 16);
}
__device__ __forceinline__ void gload_lds16(const void* g, void* l) {
  __builtin_amdgcn_global_load_lds(
      (const __attribute__((address_space(1))) void*)g,
      (__attribute__((address_space(3))) void*)l, 16, 0, 0);
}

// ---------------- weight prep kernels ----------------
// WT[o][k] = bf16(W[k][o]);  grid = N blocks (one per o), 256 threads
__global__ __launch_bounds__(256) void k_castT(const float* __restrict__ W,
                                               u16* __restrict__ WT, int K, int N) {
  int o = blockIdx.x;
  for (int k = threadIdx.x; k < K; k += 256)
    WT[(size_t)o * K + k] = f2bf(W[(size_t)k * N + o]);
}

// straight cast conv_w [1024][4096] f32 -> bf16 ; grid 4096 x 256, 1 float4/thread
__global__ __launch_bounds__(256) void k_cast4(const float* __restrict__ W,
                                               u16* __restrict__ Wb) {
  int i = blockIdx.x * 256 + threadIdx.x;
  float4 f = ((const float4*)W)[i];
  ushort4 u; u.x = f2bf(f.x); u.y = f2bf(f.y); u.z = f2bf(f.z); u.w = f2bf(f.w);
  ((ushort4*)Wb)[i] = u;
}

// XGbf[bg][ik] = bf16(x[b][4g+(ik&3)][ik>>2]) ; grid 128 blocks
__global__ __launch_bounds__(256) void k_xg(const float* __restrict__ x,
                                            u16* __restrict__ XG) {
  int bg = blockIdx.x;
  int b = bg >> 6, g = bg & 63;
  for (int ik = threadIdx.x; ik < 4096; ik += 256)
    XG[(size_t)bg * 4096 + ik] =
        f2bf(x[((size_t)b * SEQ + g * 4 + (ik & 3)) * HID + (ik >> 2)]);
}

// gt rows 64..127 <- global memory tokens; grid 512 x 256 (exact)
__global__ __launch_bounds__(256) void k_gtmem(const float* __restrict__ gm,
                                               float* __restrict__ gt) {
  int i = blockIdx.x * 256 + threadIdx.x;   // 0..131071
  int c = i & 1023, g = (i >> 10) & 63, b = i >> 16;
  gt[((size_t)(b * 128 + 64 + g)) * HID + c] =
      gm[((size_t)(c >> 6) * 64 + g) * 64 + (c & 63)];
}

// ---------------- generic 128x128 bf16 MFMA GEMM, B^T layout ----------------
// C[r][o] = sum_k A[r][k]*Bt[o][k]  (+ fused epilogue)
// EPI 0: gt = acc + conv_b           (M=128 rows map to (b,g))
// EPI 1: gate/mix epilogue -> mixedbf
// EPI 2: d_out = acc + out_b
template <int EPI>
__global__ __launch_bounds__(256) void gemm_bt(
    const u16* __restrict__ A, const u16* __restrict__ Bt, int M, int N, int K,
    const float* __restrict__ bias, float* __restrict__ outf,
    u16* __restrict__ outbf, const float* __restrict__ bcast) {
  __shared__ __align__(16) u16 As[128 * 64];
  __shared__ __align__(16) u16 Bs[128 * 64];
  const int nbn = N >> 7;
  const int bm = blockIdx.x / nbn, bn = blockIdx.x % nbn;
  const int tid = threadIdx.x;
  const int lane = tid & 63, wid = tid >> 6;
  const int wm = wid >> 1, wn = wid & 1;
  const int l15 = lane & 15, l4 = lane >> 4;
  f32x4 acc[4][4] = {};
  const int srow = tid >> 3, scol = (tid & 7) * 8;
  const u16* gA = A + (size_t)(bm * 128 + srow) * K + scol;
  const u16* gB = Bt + (size_t)(bn * 128 + srow) * K + scol;

  for (int k0 = 0; k0 < K; k0 += 64) {
#pragma unroll
    for (int r4 = 0; r4 < 4; ++r4) {
      gload_lds16(gA + (size_t)32 * r4 * K + k0, &As[(srow + 32 * r4) * 64 + scol]);
      gload_lds16(gB + (size_t)32 * r4 * K + k0, &Bs[(srow + 32 * r4) * 64 + scol]);
    }
    __syncthreads();
#pragma unroll
    for (int ks = 0; ks < 2; ++ks) {
      bf16x8 af[4], bv[4];
#pragma unroll
      for (int m = 0; m < 4; ++m)
        af[m] = *(const bf16x8*)&As[(wm * 64 + m * 16 + l15) * 64 + ks * 32 + l4 * 8];
#pragma unroll
      for (int n = 0; n < 4; ++n)
        bv[n] = *(const bf16x8*)&Bs[(wn * 64 + n * 16 + l15) * 64 + ks * 32 + l4 * 8];
#pragma unroll
      for (int m = 0; m < 4; ++m)
#pragma unroll
        for (int n = 0; n < 4; ++n)
          acc[m][n] = __builtin_amdgcn_mfma_f32_16x16x32_bf16(af[m], bv[n], acc[m][n], 0, 0, 0);
    }
    __syncthreads();
  }

  const int row0 = bm * 128 + wm * 64, col0 = bn * 128 + wn * 64;
#pragma unroll
  for (int m = 0; m < 4; ++m)
#pragma unroll
    for (int n = 0; n < 4; ++n)
#pragma unroll
      for (int r = 0; r < 4; ++r) {
        int row = row0 + m * 16 + l4 * 4 + r;
        int col = col0 + n * 16 + l15;
        float v = acc[m][n][r];
        if (EPI == 0) {
          v += bias[col];
          outf[((size_t)((row >> 6) * 128 + (row & 63))) * HID + col] = v;
        } else if (EPI == 1) {
          float gate = 1.f / (1.f + __expf(-(v + bias[col])));
          float lv = bf2f(A[(size_t)row * K + col]);
          float gv = bf2f(A[(size_t)row * K + 1024 + col]);
          float mx = gate * lv + (1.f - gate) * gv + bcast[(size_t)row * HID + col];
          outbf[(size_t)row * HID + col] = f2bf(mx);
        } else {
          outf[(size_t)row * HID + col] = v + bias[col];
        }
      }
}

// ---------------- flash attention (MFMA 16x16x32), shared structure ----------------
// Per block: 4 waves x 32 q-rows = 128 q rows, one head-slice (64 dims).
// K/V chunks of 64 staged to LDS (K row-major [k][d], V transposed [d][k]).

__global__ __launch_bounds__(256) void k_attn_swa(const float* __restrict__ x,
                                                  u16* __restrict__ ow) {
  __shared__ __align__(16) u16 qs[128 * 64];
  __shared__ __align__(16) u16 kts[64 * 64];
  __shared__ __align__(16) u16 vsT[64 * 72];
  __shared__ __align__(16) u16 ps[4 * 32 * 64];
  const int blk = blockIdx.x;
  const int b = blk / 960;
  int rem = blk % 960;
  const int n = rem / 64;  rem &= 63;
  const int h = rem >> 2, qc = rem & 3;
  const int tid = threadIdx.x, lane = tid & 63, wid = tid >> 6;
  const int l15 = lane & 15, l4 = lane >> 4;
  const float* xb = x + (size_t)b * SEQ * HID + h * 64;
  const int q0 = n * STRW + qc * 128;
  {  // stage Q (128 x 64)
    const int r = tid >> 1, c0 = (tid & 1) * 32;
    const float* src = xb + (size_t)(q0 + r) * HID + c0;
#pragma unroll
    for (int j = 0; j < 32; j += 4) {
      float4 f = *(const float4*)(src + j);
      ushort4 u; u.x = f2bf(f.x); u.y = f2bf(f.y); u.z = f2bf(f.z); u.w = f2bf(f.w);
      *(ushort4*)&qs[r * 64 + c0 + j] = u;
    }
  }
  float m_run[2][4], l_run[2][4];
  f32x4 Oc[2][4] = {};
#pragma unroll
  for (int m = 0; m < 2; ++m)
#pragma unroll
    for (int r = 0; r < 4; ++r) { m_run[m][r] = -1e30f; l_run[m][r] = 0.f; }

  for (int c = 0; c < 8; ++c) {
    __syncthreads();
    {  // stage K chunk (64 x 64) + transposed V
      const int r = tid >> 2, c0 = (tid & 3) * 16;
      const float* src = xb + (size_t)(n * STRW + c * 64 + r) * HID + c0;
#pragma unroll
      for (int j = 0; j < 16; j += 4) {
        float4 f = *(const float4*)(src + j);
        u16 u0 = f2bf(f.x), u1 = f2bf(f.y), u2 = f2bf(f.z), u3 = f2bf(f.w);
        ushort4 u; u.x = u0; u.y = u1; u.z = u2; u.w = u3;
        *(ushort4*)&kts[r * 64 + c0 + j] = u;
        vsT[(c0 + j + 0) * 72 + r] = u0;
        vsT[(c0 + j + 1) * 72 + r] = u1;
        vsT[(c0 + j + 2) * 72 + r] = u2;
        vsT[(c0 + j + 3) * 72 + r] = u3;
      }
    }
    __syncthreads();
    float sv[2][4][4];
#pragma unroll
    for (int m = 0; m < 2; ++m)
#pragma unroll
      for (int nf = 0; nf < 4; ++nf) {
        f32x4 s = {};
#pragma unroll
        for (int ks = 0; ks < 2; ++ks) {
          bf16x8 a = *(const bf16x8*)&qs[(wid * 32 + m * 16 + l15) * 64 + ks * 32 + l4 * 8];
          bf16x8 bb = *(const bf16x8*)&kts[(nf * 16 + l15) * 64 + ks * 32 + l4 * 8];
          s = __builtin_amdgcn_mfma_f32_16x16x32_bf16(a, bb, s, 0, 0, 0);
        }
#pragma unroll
        for (int r = 0; r < 4; ++r) sv[m][nf][r] = s[r] * 0.125f;
      }
#pragma unroll
    for (int m = 0; m < 2; ++m)
#pragma unroll
      for (int r = 0; r < 4; ++r) {
        float mx = fmaxf(fmaxf(sv[m][0][r], sv[m][1][r]), fmaxf(sv[m][2][r], sv[m][3][r]));
#pragma unroll
        for (int msk = 1; msk < 16; msk <<= 1) mx = fmaxf(mx, __shfl_xor(mx, msk, 64));
        float mnew = fmaxf(m_run[m][r], mx);
        float alpha = __expf(m_run[m][r] - mnew);
        m_run[m][r] = mnew;
        float rs = 0.f;
#pragma unroll
        for (int nf = 0; nf < 4; ++nf) {
          float p = __expf(sv[m][nf][r] - mnew);
          sv[m][nf][r] = p; rs += p;
        }
#pragma unroll
        for (int msk = 1; msk < 16; msk <<= 1) rs += __shfl_xor(rs, msk, 64);
        l_run[m][r] = l_run[m][r] * alpha + rs;
#pragma unroll
        for (int nf = 0; nf < 4; ++nf) Oc[m][nf][r] = Oc[m][nf][r] * alpha;
      }
#pragma unroll
    for (int m = 0; m < 2; ++m)
#pragma unroll
      for (int nf = 0; nf < 4; ++nf)
#pragma unroll
        for (int r = 0; r < 4; ++r)
          ps[wid * 2048 + (m * 16 + l4 * 4 + r) * 64 + nf * 16 + l15] = f2bf(sv[m][nf][r]);
    asm volatile("s_waitcnt lgkmcnt(0)" ::: "memory");
#pragma unroll
    for (int m = 0; m < 2; ++m)
#pragma unroll
      for (int nf = 0; nf < 4; ++nf) {
        f32x4 o = Oc[m][nf];
#pragma unroll
        for (int ks = 0; ks < 2; ++ks) {
          bf16x8 a = *(const bf16x8*)&ps[wid * 2048 + (m * 16 + l15) * 64 + ks * 32 + l4 * 8];
          bf16x8 bb = *(const bf16x8*)&vsT[(nf * 16 + l15) * 72 + ks * 32 + l4 * 8];
          o = __builtin_amdgcn_mfma_f32_16x16x32_bf16(a, bb, o, 0, 0, 0);
        }
        Oc[m][nf] = o;
      }
  }
#pragma unroll
  for (int m = 0; m < 2; ++m)
#pragma unroll
    for (int nf = 0; nf < 4; ++nf)
#pragma unroll
      for (int r = 0; r < 4; ++r) {
        int qoff = qc * 128 + wid * 32 + m * 16 + l4 * 4 + r;
        float tri = 0.5f + (float)qoff * (1.0f / 511.0f);
        float val = Oc[m][nf][r] / l_run[m][r] * tri;
        ow[((size_t)(b * 15 + n) * 512 + qoff) * 1024 + h * 64 + nf * 16 + l15] = f2bf(val);
      }
}

__global__ __launch_bounds__(256) void k_attn_glob(const float* __restrict__ x,
                                                   const float* __restrict__ gt,
                                                   u16* __restrict__ abf) {
  __shared__ __align__(16) u16 qs[128 * 64];
  __shared__ __align__(16) u16 kts[64 * 64];
  __shared__ __align__(16) u16 vsT[64 * 72];
  __shared__ __align__(16) u16 ps[4 * 32 * 64];
  const int blk = blockIdx.x;
  const int b = blk >> 9, h = (blk >> 5) & 15, qc = blk & 31;
  const int tid = threadIdx.x, lane = tid & 63, wid = tid >> 6;
  const int l15 = lane & 15, l4 = lane >> 4;
  const float* xb = x + (size_t)b * SEQ * HID + h * 64;
  const float* gtb = gt + (size_t)b * 128 * HID + h * 64;
  const int q0 = qc * 128;
  {
    const int r = tid >> 1, c0 = (tid & 1) * 32;
    const float* src = xb + (size_t)(q0 + r) * HID + c0;
#pragma unroll
    for (int j = 0; j < 32; j += 4) {
      float4 f = *(const float4*)(src + j);
      ushort4 u; u.x = f2bf(f.x); u.y = f2bf(f.y); u.z = f2bf(f.z); u.w = f2bf(f.w);
      *(ushort4*)&qs[r * 64 + c0 + j] = u;
    }
  }
  float m_run[2][4], l_run[2][4];
  f32x4 Oc[2][4] = {};
#pragma unroll
  for (int m = 0; m < 2; ++m)
#pragma unroll
    for (int r = 0; r < 4; ++r) { m_run[m][r] = -1e30f; l_run[m][r] = 0.f; }

  for (int c = 0; c < 2; ++c) {
    __syncthreads();
    {
      const int r = tid >> 2, c0 = (tid & 3) * 16;
      const float* src = gtb + (size_t)(c * 64 + r) * HID + c0;
#pragma unroll
      for (int j = 0; j < 16; j += 4) {
        float4 f = *(const float4*)(src + j);
        u16 u0 = f2bf(f.x), u1 = f2bf(f.y), u2 = f2bf(f.z), u3 = f2bf(f.w);
        ushort4 u; u.x = u0; u.y = u1; u.z = u2; u.w = u3;
        *(ushort4*)&kts[r * 64 + c0 + j] = u;
        vsT[(c0 + j + 0) * 72 + r] = u0;
        vsT[(c0 + j + 1) * 72 + r] = u1;
        vsT[(c0 + j + 2) * 72 + r] = u2;
        vsT[(c0 + j + 3) * 72 + r] = u3;
      }
    }
    __syncthreads();
    float sv[2][4][4];
#pragma unroll
    for (int m = 0; m < 2; ++m)
#pragma unroll
      for (int nf = 0; nf < 4; ++nf) {
        f32x4 s = {};
#pragma unroll
        for (int ks = 0; ks < 2; ++ks) {
          bf16x8 a = *(const bf16x8*)&qs[(wid * 32 + m * 16 + l15) * 64 + ks * 32 + l4 * 8];
          bf16x8 bb = *(const bf16x8*)&kts[(nf * 16 + l15) * 64 + ks * 32 + l4 * 8];
          s = __builtin_amdgcn_mfma_f32_16x16x32_bf16(a, bb, s, 0, 0, 0);
        }
#pragma unroll
        for (int r = 0; r < 4; ++r) sv[m][nf][r] = s[r] * 0.125f;
      }
#pragma unroll
    for (int m = 0; m < 2; ++m)
#pragma unroll
      for (int r = 0; r < 4; ++r) {
        float mx = fmaxf(fmaxf(sv[m][0][r], sv[m][1][r]), fmaxf(sv[m][2][r], sv[m][3][r]));
#pragma unroll
        for (int msk = 1; msk < 16; msk <<= 1) mx = fmaxf(mx, __shfl_xor(mx, msk, 64));
        float mnew = fmaxf(m_run[m][r], mx);
        float alpha = __expf(m_run[m][r] - mnew);
        m_run[m][r] = mnew;
        float rs = 0.f;
#pragma unroll
        for (int nf = 0; nf < 4; ++nf) {
          float p = __expf(sv[m][nf][r] - mnew);
          sv[m][nf][r] = p; rs += p;
        }
#pragma unroll
        for (int msk = 1; msk < 16; msk <<= 1) rs += __shfl_xor(rs, msk, 64);
        l_run[m][r] = l_run[m][r] * alpha + rs;
#pragma unroll
        for (int nf = 0; nf < 4; ++nf) Oc[m][nf][r] = Oc[m][nf][r] * alpha;
      }
#pragma unroll
    for (int m = 0; m < 2; ++m)
#pragma unroll
      for (int nf = 0; nf < 4; ++nf)
#pragma unroll
        for (int r = 0; r < 4; ++r)
          ps[wid * 2048 + (m * 16 + l4 * 4 + r) * 64 + nf * 16 + l15] = f2bf(sv[m][nf][r]);
    asm volatile("s_waitcnt lgkmcnt(0)" ::: "memory");
#pragma unroll
    for (int m = 0; m < 2; ++m)
#pragma unroll
      for (int nf = 0; nf < 4; ++nf) {
        f32x4 o = Oc[m][nf];
#pragma unroll
        for (int ks = 0; ks < 2; ++ks) {
          bf16x8 a = *(const bf16x8*)&ps[wid * 2048 + (m * 16 + l15) * 64 + ks * 32 + l4 * 8];
          bf16x8 bb = *(const bf16x8*)&vsT[(nf * 16 + l15) * 72 + ks * 32 + l4 * 8];
          o = __builtin_amdgcn_mfma_f32_16x16x32_bf16(a, bb, o, 0, 0, 0);
        }
        Oc[m][nf] = o;
      }
  }
#pragma unroll
  for (int m = 0; m < 2; ++m)
#pragma unroll
    for (int nf = 0; nf < 4; ++nf)
#pragma unroll
      for (int r = 0; r < 4; ++r) {
        int s = q0 + wid * 32 + m * 16 + l4 * 4 + r;
        float val = Oc[m][nf][r] / l_run[m][r];
        abf[((size_t)(b * SEQ + s)) * 2048 + 1024 + h * 64 + nf * 16 + l15] = f2bf(val);
      }
}

// combine tri-weighted window outputs -> local (bf16, into Abf cols 0..1023)
__global__ __launch_bounds__(256) void k_combine(const u16* __restrict__ ow,
                                                 u16* __restrict__ abf) {
  int idx = blockIdx.x * 256 + threadIdx.x;  // over 2*4096*128 = 2^20
  int c8 = idx & 127;
  int s = (idx >> 7) & 4095;
  int b = idx >> 19;
  float acc0 = 0, acc1 = 0, acc2 = 0, acc3 = 0, acc4 = 0, acc5 = 0, acc6 = 0, acc7 = 0;
  float den = 1e-6f;
  int nb = s >> 8, off = s & 255;
  if (nb <= 14) {
    uint4 u = *(const uint4*)(ow + ((size_t)(b * 15 + nb) * 512 + off) * 1024 + c8 * 8);
    acc0 += bf2f(u.x & 0xffff); acc1 += bf2f(u.x >> 16);
    acc2 += bf2f(u.y & 0xffff); acc3 += bf2f(u.y >> 16);
    acc4 += bf2f(u.z & 0xffff); acc5 += bf2f(u.z >> 16);
    acc6 += bf2f(u.w & 0xffff); acc7 += bf2f(u.w >> 16);
    den += 0.5f + off * (1.f / 511.f);
  }
  if (nb >= 1) {
    int off2 = off + 256;
    uint4 u = *(const uint4*)(ow + ((size_t)(b * 15 + nb - 1) * 512 + off2) * 1024 + c8 * 8);
    acc0 += bf2f(u.x & 0xffff); acc1 += bf2f(u.x >> 16);
    acc2 += bf2f(u.y & 0xffff); acc3 += bf2f(u.y >> 16);
    acc4 += bf2f(u.z & 0xffff); acc5 += bf2f(u.z >> 16);
    acc6 += bf2f(u.w & 0xffff); acc7 += bf2f(u.w >> 16);
    den += 0.5f + off2 * (1.f / 511.f);
  }
  float inv = 1.f / den;
  uint4 o;
  o.x = (u32)f2bf(acc0 * inv) | ((u32)f2bf(acc1 * inv) << 16);
  o.y = (u32)f2bf(acc2 * inv) | ((u32)f2bf(acc3 * inv) << 16);
  o.z = (u32)f2bf(acc4 * inv) | ((u32)f2bf(acc5 * inv) << 16);
  o.w = (u32)f2bf(acc6 * inv) | ((u32)f2bf(acc7 * inv) << 16);
  *(uint4*)(abf + ((size_t)(b * SEQ + s)) * 2048 + c8 * 8) = o;
}

// information broadcast: per block 2 channels, full S column in LDS, 12 exact f32 iters
__global__ __launch_bounds__(256) void k_bcast(const float* __restrict__ x,
                                               float* __restrict__ bc) {
  __shared__ float cur[2][4096];
  const int b = blockIdx.x >> 9;
  const int c0 = (blockIdx.x & 511) * 2;
  const int t = threadIdx.x;
  float cv[2][16], res[2][16];
#pragma unroll
  for (int j = 0; j < 16; ++j) {
    int r = t + 256 * j;
    float2 v = *(const float2*)&x[((size_t)b * SEQ + r) * HID + c0];
    cv[0][j] = v.x; cv[1][j] = v.y;
    cur[0][r] = v.x; cur[1][r] = v.y;
    res[0][j] = 0.f; res[1][j] = 0.f;
  }
  __syncthreads();
  for (int sh = 1; sh < 4096; sh <<= 1) {
    float nv[2][16];
#pragma unroll
    for (int j = 0; j < 16; ++j) {
      int r = t + 256 * j;
      int rm = (r - sh) & 4095, rp = (r + sh) & 4095;
      nv[0][j] = cv[0][j] + 0.5f * (cur[0][rm] + cur[0][rp]);
      nv[1][j] = cv[1][j] + 0.5f * (cur[1][rm] + cur[1][rp]);
    }
    __syncthreads();
#pragma unroll
    for (int j = 0; j < 16; ++j) {
      int r = t + 256 * j;
      cur[0][r] = nv[0][j]; cur[1][r] = nv[1][j];
      cv[0][j] = nv[0][j];  cv[1][j] = nv[1][j];
      res[0][j] += nv[0][j]; res[1][j] += nv[1][j];
    }
    __syncthreads();
  }
#pragma unroll
  for (int j = 0; j < 16; ++j) {
    int r = t + 256 * j;
    float2 o; o.x = res[0][j] * (1.f / 13.f); o.y = res[1][j] * (1.f / 13.f);
    *(float2*)&bc[((size_t)b * SEQ + r) * HID + c0] = o;
  }
}

// ---------------- launcher ----------------
extern "C" void kernel_launch(void* const* d_in, const int* in_sizes, int n_in,
                              void* d_out, int out_size, void* d_ws, size_t ws_size,
                              hipStream_t stream) {
  (void)in_sizes; (void)n_in; (void)out_size;
  const float* x      = (const float*)d_in[0];
  const float* gm     = (const float*)d_in[1];
  const float* conv_w = (const float*)d_in[2];
  const float* conv_b = (const float*)d_in[3];
  const float* mix_w  = (const float*)d_in[4];
  const float* mix_b  = (const float*)d_in[5];
  const float* out_w  = (const float*)d_in[6];
  const float* out_b  = (const float*)d_in[7];
  float* out = (float*)d_out;
  char* ws = (char*)d_ws;
  if (ws_size < 132120576ull) return;  // need ~132 MB

  float* gt      = (float*)(ws + 0);          //  1 MB  [2][128][1024] f32
  u16*   XGbf    = (u16*)(ws + 1048576);      //  1 MB  [128][4096] bf16
  u16*   convWbf = (u16*)(ws + 2097152);      //  8 MB  [1024][4096] bf16
  u16*   mixWT   = (u16*)(ws + 10485760);     //  4 MB  [1024][2048] bf16
  u16*   outWT   = (u16*)(ws + 14680064);     //  2 MB  [1024][1024] bf16
  u16*   ow      = (u16*)(ws + 16777216);     // 30 MB  [2][15][512][1024] bf16
  u16*   Abf     = (u16*)(ws + 48234496);     // 32 MB  [8192][2048] bf16
  float* bcast   = (float*)(ws + 81788928);   // 32 MB  [8192][1024] f32
  u16*   mixedbf = (u16*)(ws + 115343360);    // 16 MB  [8192][1024] bf16

  k_castT<<<1024, 256, 0, stream>>>(mix_w, mixWT, 2048, 1024);
  k_castT<<<1024, 256, 0, stream>>>(out_w, outWT, 1024, 1024);
  k_cast4<<<4096, 256, 0, stream>>>(conv_w, convWbf);
  k_xg<<<128, 256, 0, stream>>>(x, XGbf);
  gemm_bt<0><<<8, 256, 0, stream>>>(XGbf, convWbf, 128, 1024, 4096, conv_b, gt, nullptr, nullptr);
  k_gtmem<<<512, 256, 0, stream>>>(gm, gt);
  k_attn_glob<<<1024, 256, 0, stream>>>(x, gt, Abf);
  k_attn_swa<<<1920, 256, 0, stream>>>(x, ow);
  k_combine<<<4096, 256, 0, stream>>>(ow, Abf);
  k_bcast<<<1024, 256, 0, stream>>>(x, bcast);
  gemm_bt<1><<<512, 256, 0, stream>>>(Abf, mixWT, 8192, 1024, 2048, mix_b, nullptr, mixedbf, bcast);
  gemm_bt<2><<<512, 256, 0, stream>>>(mixedbf, outWT, 8192, 1024, 1024, out_b, out, nullptr, nullptr);
}

// Round 2
// 369.726 us; speedup vs baseline: 1.3302x; 1.3302x over previous
//
#include <hip/hip_runtime.h>
#include <hip/hip_bf16.h>
#include <cstdint>

#define NHEAD 16
#define WINL  512
#define STRW  256
#define BATCH 2
#define SEQ   4096
#define HID   1024

using bf16x8 = __attribute__((ext_vector_type(8))) short;
using f32x4  = __attribute__((ext_vector_type(4))) float;
typedef unsigned short u16;
typedef unsigned int   u32;

__device__ __forceinline__ u16 f2bf(float f) {
  u32 u = __builtin_bit_cast(u32, f);
  u += 0x7fffu + ((u >> 16) & 1u);           // RNE
  return (u16)(u >> 16);
}
__device__ __forceinline__ float bf2f(u16 s) {
  return __builtin_bit_cast(float, (u32)s << 16);
}
__device__ __forceinline__ void gload_lds16(const void* g, void* l) {
  __builtin_amdgcn_global_load_lds(
      (const __attribute__((address_space(1))) void*)g,
      (__attribute__((address_space(3))) void*)l, 16, 0, 0);
}

// ---------------- prep kernels ----------------
// x f32 -> xbf bf16, fully coalesced; grid 4096 x 256 (8 els/thread)
__global__ __launch_bounds__(256) void k_xbf(const float* __restrict__ x,
                                             u16* __restrict__ xb) {
  size_t i = (size_t)blockIdx.x * 256 + threadIdx.x;
  float4 f0 = ((const float4*)x)[2 * i];
  float4 f1 = ((const float4*)x)[2 * i + 1];
  uint4 o;
  o.x = (u32)f2bf(f0.x) | ((u32)f2bf(f0.y) << 16);
  o.y = (u32)f2bf(f0.z) | ((u32)f2bf(f0.w) << 16);
  o.z = (u32)f2bf(f1.x) | ((u32)f2bf(f1.y) << 16);
  o.w = (u32)f2bf(f1.z) | ((u32)f2bf(f1.w) << 16);
  ((uint4*)xb)[i] = o;
}

// LDS-tiled transpose + cast: WT[n][k] = bf16(W[k][n]); grid (K/64)*(N/64)
__global__ __launch_bounds__(256) void k_transpose(const float* __restrict__ W,
                                                   u16* __restrict__ WT, int K, int N) {
  __shared__ u16 t[64][72];
  const int nk = K >> 6;
  const int tk = blockIdx.x % nk, tn = blockIdx.x / nk;
  const int tid = threadIdx.x;
  const int lr = tid >> 4, lc = tid & 15;
#pragma unroll
  for (int rr = 0; rr < 4; ++rr) {
    int row = lr + rr * 16;
    float4 f = *(const float4*)&W[(size_t)(tk * 64 + row) * N + tn * 64 + lc * 4];
    t[row][lc * 4 + 0] = f2bf(f.x);
    t[row][lc * 4 + 1] = f2bf(f.y);
    t[row][lc * 4 + 2] = f2bf(f.z);
    t[row][lc * 4 + 3] = f2bf(f.w);
  }
  __syncthreads();
  const int orow = tid >> 2, oq = tid & 3;
  u32 pk[8];
#pragma unroll
  for (int j = 0; j < 8; ++j) {
    u16 a = t[oq * 16 + 2 * j][orow];
    u16 b = t[oq * 16 + 2 * j + 1][orow];
    pk[j] = (u32)a | ((u32)b << 16);
  }
  uint4 o0; o0.x = pk[0]; o0.y = pk[1]; o0.z = pk[2]; o0.w = pk[3];
  uint4 o1; o1.x = pk[4]; o1.y = pk[5]; o1.z = pk[6]; o1.w = pk[7];
  size_t base = (size_t)(tn * 64 + orow) * K + tk * 64 + oq * 16;
  *(uint4*)&WT[base] = o0;
  *(uint4*)&WT[base + 8] = o1;
}

// straight cast conv_w [1024][4096] f32 -> bf16 ; grid 4096 x 256
__global__ __launch_bounds__(256) void k_cast4(const float* __restrict__ W,
                                               u16* __restrict__ Wb) {
  int i = blockIdx.x * 256 + threadIdx.x;
  float4 f = ((const float4*)W)[i];
  ushort4 u; u.x = f2bf(f.x); u.y = f2bf(f.y); u.z = f2bf(f.z); u.w = f2bf(f.w);
  ((ushort4*)Wb)[i] = u;
}

// XG[bg][i*4+t] = bf16(x[b][4g+t][i]) ; coalesced reads; grid 128 blocks
__global__ __launch_bounds__(256) void k_xg(const float* __restrict__ x,
                                            u16* __restrict__ XG) {
  int bg = blockIdx.x, b = bg >> 6, g = bg & 63;
  int rr = threadIdx.x >> 6, f4 = threadIdx.x & 63;
  const float* src = x + ((size_t)(b * SEQ + g * 4 + rr)) * HID;
  u16* dst = XG + (size_t)bg * 4096;
#pragma unroll
  for (int rep = 0; rep < 4; ++rep) {
    int c4 = rep * 64 + f4;
    float4 f = *(const float4*)&src[c4 * 4];
    dst[(c4 * 4 + 0) * 4 + rr] = f2bf(f.x);
    dst[(c4 * 4 + 1) * 4 + rr] = f2bf(f.y);
    dst[(c4 * 4 + 2) * 4 + rr] = f2bf(f.z);
    dst[(c4 * 4 + 3) * 4 + rr] = f2bf(f.w);
  }
}

// reduce conv split-K partials + bias, and append global-memory tokens -> gtbf
__global__ __launch_bounds__(256) void k_gtfin(const float* __restrict__ part,
                                               const float* __restrict__ gm,
                                               const float* __restrict__ cb,
                                               u16* __restrict__ gtbf) {
  int i = blockIdx.x * 256 + threadIdx.x;       // 2*128*1024 = 262144
  int col = i & 1023, row = (i >> 10) & 127, b = i >> 17;
  float v;
  if (row < 64) {
    v = cb[col];
#pragma unroll
    for (int kc = 0; kc < 8; ++kc)
      v += part[(size_t)kc * 131072 + (size_t)(b * 64 + row) * 1024 + col];
  } else {
    int g = row - 64;
    v = gm[((size_t)(col >> 6) * 64 + g) * 64 + (col & 63)];
  }
  gtbf[(size_t)(b * 128 + row) * 1024 + col] = f2bf(v);
}

// ---------------- 128x128 bf16 MFMA GEMM, B^T layout, swizzled LDS ----------------
// EPI 0: partial f32 (split-K, no bias)   EPI 1: gate/mix epilogue   EPI 2: bias+out
template <int EPI>
__global__ __launch_bounds__(256) void gemm_bt(
    const u16* __restrict__ A, const u16* __restrict__ Bt,
    int M, int N, int kext, int lda, int ldb, int nbn,
    const float* __restrict__ bias, float* __restrict__ outf,
    u16* __restrict__ outbf, const float* __restrict__ bcast) {
  __shared__ __align__(16) u16 As[128 * 64];
  __shared__ __align__(16) u16 Bs[128 * 64];
  const int nwg = gridDim.x;
  int id = blockIdx.x;
  id = (id & 7) * (nwg >> 3) + (id >> 3);        // XCD swizzle (nwg % 8 == 0)
  const int nbm = M >> 7;
  const int per = nbm * nbn;
  const int kc = id / per;
  int rem = id % per;
  const int bm = rem / nbn, bn = rem % nbn;
  const int tid = threadIdx.x;
  const int lane = tid & 63, wid = tid >> 6;
  const int wm = wid >> 1, wn = wid & 1;
  const int l15 = lane & 15, l4 = lane >> 4;
  f32x4 acc[4][4] = {};
  const int srow = tid >> 3, cg = tid & 7;
  const u16* gA = A + (size_t)(bm * 128) * lda + (size_t)kc * kext;
  const u16* gB = Bt + (size_t)(bn * 128) * ldb + (size_t)kc * kext;

  for (int k0 = 0; k0 < kext; k0 += 64) {
#pragma unroll
    for (int r4 = 0; r4 < 4; ++r4) {
      int row = srow + 32 * r4;
      int sc = ((cg ^ (row & 7)) << 3);
      gload_lds16(gA + (size_t)row * lda + k0 + sc, &As[row * 64 + cg * 8]);
      gload_lds16(gB + (size_t)row * ldb + k0 + sc, &Bs[row * 64 + cg * 8]);
    }
    __syncthreads();
#pragma unroll
    for (int ks = 0; ks < 2; ++ks) {
      bf16x8 af[4], bv[4];
#pragma unroll
      for (int m = 0; m < 4; ++m) {
        int row = wm * 64 + m * 16 + l15;
        af[m] = *(const bf16x8*)&As[row * 64 + (((ks * 4 + l4) ^ (row & 7)) << 3)];
      }
#pragma unroll
      for (int n = 0; n < 4; ++n) {
        int row = wn * 64 + n * 16 + l15;
        bv[n] = *(const bf16x8*)&Bs[row * 64 + (((ks * 4 + l4) ^ (row & 7)) << 3)];
      }
#pragma unroll
      for (int m = 0; m < 4; ++m)
#pragma unroll
        for (int n = 0; n < 4; ++n)
          acc[m][n] = __builtin_amdgcn_mfma_f32_16x16x32_bf16(af[m], bv[n], acc[m][n], 0, 0, 0);
    }
    __syncthreads();
  }

  const int row0 = bm * 128 + wm * 64, col0 = bn * 128 + wn * 64;
#pragma unroll
  for (int m = 0; m < 4; ++m)
#pragma unroll
    for (int n = 0; n < 4; ++n)
#pragma unroll
      for (int r = 0; r < 4; ++r) {
        int row = row0 + m * 16 + l4 * 4 + r;
        int col = col0 + n * 16 + l15;
        float v = acc[m][n][r];
        if (EPI == 0) {
          outf[(size_t)kc * M * N + (size_t)row * N + col] = v;
        } else if (EPI == 1) {
          float gate = 1.f / (1.f + __expf(-(v + bias[col])));
          float lv = bf2f(A[(size_t)row * lda + col]);
          float gv = bf2f(A[(size_t)row * lda + 1024 + col]);
          float mx = gate * lv + (1.f - gate) * gv + bcast[(size_t)row * HID + col];
          outbf[(size_t)row * HID + col] = f2bf(mx);
        } else {
          outf[(size_t)row * N + col] = v + bias[col];
        }
      }
}

// ---------------- flash attention (MFMA 16x16x32), bf16 inputs, swizzled LDS ----------------
__global__ __launch_bounds__(256) void k_attn_swa(const u16* __restrict__ xbf,
                                                  u16* __restrict__ ow) {
  __shared__ __align__(16) u16 kts[64 * 64];     // K chunk, granule-swizzled
  __shared__ __align__(16) u16 vsT[64 * 72];     // V^T [d][k], pad 72
  __shared__ __align__(16) u16 ps[4 * 32 * 64];  // per-wave P, s2-swizzled
  const int blk = blockIdx.x;
  const int b = blk / 960;
  int rem = blk % 960;
  const int n = rem / 64;  rem &= 63;
  const int h = rem >> 2, qc = rem & 3;
  const int tid = threadIdx.x, lane = tid & 63, wid = tid >> 6;
  const int l15 = lane & 15, l4 = lane >> 4;
  const int q0 = n * STRW + qc * 128;

  bf16x8 qf[2][2];   // Q fragments in registers
  {
    const u16* xq = xbf + ((size_t)(b * SEQ + q0 + wid * 32 + l15)) * HID + h * 64 + l4 * 8;
#pragma unroll
    for (int m = 0; m < 2; ++m)
#pragma unroll
      for (int ks = 0; ks < 2; ++ks)
        qf[m][ks] = *(const bf16x8*)(xq + (size_t)m * 16 * HID + ks * 32);
  }
  const int prow0 = wid * 16 + (lane >> 3);
  const int cg = lane & 7;
  const int vr = tid & 63, vdc = (tid >> 6) * 16;

  float m_run[2][4], l_run[2][4];
  f32x4 Oc[2][4] = {};
#pragma unroll
  for (int m = 0; m < 2; ++m)
#pragma unroll
    for (int r = 0; r < 4; ++r) { m_run[m][r] = -1e30f; l_run[m][r] = 0.f; }

  for (int c = 0; c < 8; ++c) {
    const int kb = n * STRW + c * 64;
    __syncthreads();
#pragma unroll
    for (int e = 0; e < 2; ++e) {    // K: global_load_lds, pre-swizzled source
      int row = prow0 + e * 8;
      const u16* src = xbf + ((size_t)(b * SEQ + kb + row)) * HID + h * 64 + ((cg ^ (row & 7)) << 3);
      gload_lds16(src, &kts[(wid * 2 + e) * 512 + lane * 8]);
    }
    {                                // V: register transpose
      const u16* vs = xbf + ((size_t)(b * SEQ + kb + vr)) * HID + h * 64 + vdc;
      uint4 v0 = *(const uint4*)vs;
      uint4 v1 = *(const uint4*)(vs + 8);
      u32 w_[8] = {v0.x, v0.y, v0.z, v0.w, v1.x, v1.y, v1.z, v1.w};
#pragma unroll
      for (int j = 0; j < 8; ++j) {
        vsT[(vdc + 2 * j) * 72 + vr] = (u16)w_[j];
        vsT[(vdc + 2 * j + 1) * 72 + vr] = (u16)(w_[j] >> 16);
      }
    }
    __syncthreads();
    float sv[2][4][4];
#pragma unroll
    for (int m = 0; m < 2; ++m)
#pragma unroll
      for (int nf = 0; nf < 4; ++nf) {
        f32x4 s = {};
#pragma unroll
        for (int ks = 0; ks < 2; ++ks) {
          int krow = nf * 16 + l15;
          bf16x8 bb = *(const bf16x8*)&kts[krow * 64 + (((ks * 4 + l4) ^ (krow & 7)) << 3)];
          s = __builtin_amdgcn_mfma_f32_16x16x32_bf16(qf[m][ks], bb, s, 0, 0, 0);
        }
#pragma unroll
        for (int r = 0; r < 4; ++r) sv[m][nf][r] = s[r] * 0.125f;
      }
#pragma unroll
    for (int m = 0; m < 2; ++m)
#pragma unroll
      for (int r = 0; r < 4; ++r) {
        float mx = fmaxf(fmaxf(sv[m][0][r], sv[m][1][r]), fmaxf(sv[m][2][r], sv[m][3][r]));
#pragma unroll
        for (int msk = 1; msk < 16; msk <<= 1) mx = fmaxf(mx, __shfl_xor(mx, msk, 64));
        float mnew = fmaxf(m_run[m][r], mx);
        float alpha = __expf(m_run[m][r] - mnew);
        m_run[m][r] = mnew;
        float rs = 0.f;
#pragma unroll
        for (int nf = 0; nf < 4; ++nf) {
          float p = __expf(sv[m][nf][r] - mnew);
          sv[m][nf][r] = p; rs += p;
        }
#pragma unroll
        for (int msk = 1; msk < 16; msk <<= 1) rs += __shfl_xor(rs, msk, 64);
        l_run[m][r] = l_run[m][r] * alpha + rs;
#pragma unroll
        for (int nf = 0; nf < 4; ++nf) Oc[m][nf][r] = Oc[m][nf][r] * alpha;
      }
#pragma unroll
    for (int m = 0; m < 2; ++m)
#pragma unroll
      for (int nf = 0; nf < 4; ++nf)
#pragma unroll
        for (int r = 0; r < 4; ++r) {
          int row = m * 16 + l4 * 4 + r;
          int s2 = (row ^ (row >> 1)) & 7;
          ps[wid * 2048 + row * 64 + ((nf * 16 + l15) ^ (s2 << 3))] = f2bf(sv[m][nf][r]);
        }
    asm volatile("s_waitcnt lgkmcnt(0)" ::: "memory");
#pragma unroll
    for (int m = 0; m < 2; ++m) {
      int row = m * 16 + l15;
      int s2 = (row ^ (row >> 1)) & 7;
#pragma unroll
      for (int nf = 0; nf < 4; ++nf) {
        f32x4 o = Oc[m][nf];
#pragma unroll
        for (int ks = 0; ks < 2; ++ks) {
          bf16x8 a = *(const bf16x8*)&ps[wid * 2048 + row * 64 + (((ks * 4 + l4) ^ s2) << 3)];
          bf16x8 bb = *(const bf16x8*)&vsT[(nf * 16 + l15) * 72 + ks * 32 + l4 * 8];
          o = __builtin_amdgcn_mfma_f32_16x16x32_bf16(a, bb, o, 0, 0, 0);
        }
        Oc[m][nf] = o;
      }
    }
  }
#pragma unroll
  for (int m = 0; m < 2; ++m)
#pragma unroll
    for (int nf = 0; nf < 4; ++nf)
#pragma unroll
      for (int r = 0; r < 4; ++r) {
        int qoff = qc * 128 + wid * 32 + m * 16 + l4 * 4 + r;
        float tri = 0.5f + (float)qoff * (1.0f / 511.0f);
        float val = Oc[m][nf][r] / l_run[m][r] * tri;
        ow[((size_t)(b * 15 + n) * 512 + qoff) * 1024 + h * 64 + nf * 16 + l15] = f2bf(val);
      }
}

__global__ __launch_bounds__(256) void k_attn_glob(const u16* __restrict__ xbf,
                                                   const u16* __restrict__ gtbf,
                                                   u16* __restrict__ abf) {
  __shared__ __align__(16) u16 kts[64 * 64];
  __shared__ __align__(16) u16 vsT[64 * 72];
  __shared__ __align__(16) u16 ps[4 * 32 * 64];
  const int blk = blockIdx.x;
  const int b = blk >> 9, h = (blk >> 5) & 15, qc = blk & 31;
  const int tid = threadIdx.x, lane = tid & 63, wid = tid >> 6;
  const int l15 = lane & 15, l4 = lane >> 4;
  const int q0 = qc * 128;
  bf16x8 qf[2][2];
  {
    const u16* xq = xbf + ((size_t)(b * SEQ + q0 + wid * 32 + l15)) * HID + h * 64 + l4 * 8;
#pragma unroll
    for (int m = 0; m < 2; ++m)
#pragma unroll
      for (int ks = 0; ks < 2; ++ks)
        qf[m][ks] = *(const bf16x8*)(xq + (size_t)m * 16 * HID + ks * 32);
  }
  const int prow0 = wid * 16 + (lane >> 3);
  const int cg = lane & 7;
  const int vr = tid & 63, vdc = (tid >> 6) * 16;
  float m_run[2][4], l_run[2][4];
  f32x4 Oc[2][4] = {};
#pragma unroll
  for (int m = 0; m < 2; ++m)
#pragma unroll
    for (int r = 0; r < 4; ++r) { m_run[m][r] = -1e30f; l_run[m][r] = 0.f; }

  for (int c = 0; c < 2; ++c) {
    const int kb = c * 64;
    __syncthreads();
#pragma unroll
    for (int e = 0; e < 2; ++e) {
      int row = prow0 + e * 8;
      const u16* src = gtbf + ((size_t)(b * 128 + kb + row)) * HID + h * 64 + ((cg ^ (row & 7)) << 3);
      gload_lds16(src, &kts[(wid * 2 + e) * 512 + lane * 8]);
    }
    {
      const u16* vs = gtbf + ((size_t)(b * 128 + kb + vr)) * HID + h * 64 + vdc;
      uint4 v0 = *(const uint4*)vs;
      uint4 v1 = *(const uint4*)(vs + 8);
      u32 w_[8] = {v0.x, v0.y, v0.z, v0.w, v1.x, v1.y, v1.z, v1.w};
#pragma unroll
      for (int j = 0; j < 8; ++j) {
        vsT[(vdc + 2 * j) * 72 + vr] = (u16)w_[j];
        vsT[(vdc + 2 * j + 1) * 72 + vr] = (u16)(w_[j] >> 16);
      }
    }
    __syncthreads();
    float sv[2][4][4];
#pragma unroll
    for (int m = 0; m < 2; ++m)
#pragma unroll
      for (int nf = 0; nf < 4; ++nf) {
        f32x4 s = {};
#pragma unroll
        for (int ks = 0; ks < 2; ++ks) {
          int krow = nf * 16 + l15;
          bf16x8 bb = *(const bf16x8*)&kts[krow * 64 + (((ks * 4 + l4) ^ (krow & 7)) << 3)];
          s = __builtin_amdgcn_mfma_f32_16x16x32_bf16(qf[m][ks], bb, s, 0, 0, 0);
        }
#pragma unroll
        for (int r = 0; r < 4; ++r) sv[m][nf][r] = s[r] * 0.125f;
      }
#pragma unroll
    for (int m = 0; m < 2; ++m)
#pragma unroll
      for (int r = 0; r < 4; ++r) {
        float mx = fmaxf(fmaxf(sv[m][0][r], sv[m][1][r]), fmaxf(sv[m][2][r], sv[m][3][r]));
#pragma unroll
        for (int msk = 1; msk < 16; msk <<= 1) mx = fmaxf(mx, __shfl_xor(mx, msk, 64));
        float mnew = fmaxf(m_run[m][r], mx);
        float alpha = __expf(m_run[m][r] - mnew);
        m_run[m][r] = mnew;
        float rs = 0.f;
#pragma unroll
        for (int nf = 0; nf < 4; ++nf) {
          float p = __expf(sv[m][nf][r] - mnew);
          sv[m][nf][r] = p; rs += p;
        }
#pragma unroll
        for (int msk = 1; msk < 16; msk <<= 1) rs += __shfl_xor(rs, msk, 64);
        l_run[m][r] = l_run[m][r] * alpha + rs;
#pragma unroll
        for (int nf = 0; nf < 4; ++nf) Oc[m][nf][r] = Oc[m][nf][r] * alpha;
      }
#pragma unroll
    for (int m = 0; m < 2; ++m)
#pragma unroll
      for (int nf = 0; nf < 4; ++nf)
#pragma unroll
        for (int r = 0; r < 4; ++r) {
          int row = m * 16 + l4 * 4 + r;
          int s2 = (row ^ (row >> 1)) & 7;
          ps[wid * 2048 + row * 64 + ((nf * 16 + l15) ^ (s2 << 3))] = f2bf(sv[m][nf][r]);
        }
    asm volatile("s_waitcnt lgkmcnt(0)" ::: "memory");
#pragma unroll
    for (int m = 0; m < 2; ++m) {
      int row = m * 16 + l15;
      int s2 = (row ^ (row >> 1)) & 7;
#pragma unroll
      for (int nf = 0; nf < 4; ++nf) {
        f32x4 o = Oc[m][nf];
#pragma unroll
        for (int ks = 0; ks < 2; ++ks) {
          bf16x8 a = *(const bf16x8*)&ps[wid * 2048 + row * 64 + (((ks * 4 + l4) ^ s2) << 3)];
          bf16x8 bb = *(const bf16x8*)&vsT[(nf * 16 + l15) * 72 + ks * 32 + l4 * 8];
          o = __builtin_amdgcn_mfma_f32_16x16x32_bf16(a, bb, o, 0, 0, 0);
        }
        Oc[m][nf] = o;
      }
    }
  }
#pragma unroll
  for (int m = 0; m < 2; ++m)
#pragma unroll
    for (int nf = 0; nf < 4; ++nf)
#pragma unroll
      for (int r = 0; r < 4; ++r) {
        int s = q0 + wid * 32 + m * 16 + l4 * 4 + r;
        float val = Oc[m][nf][r] / l_run[m][r];
        abf[((size_t)(b * SEQ + s)) * 2048 + 1024 + h * 64 + nf * 16 + l15] = f2bf(val);
      }
}

// combine tri-weighted window outputs -> Abf cols 0..1023
__global__ __launch_bounds__(256) void k_combine(const u16* __restrict__ ow,
                                                 u16* __restrict__ abf) {
  int idx = blockIdx.x * 256 + threadIdx.x;  // 2*4096*128
  int c8 = idx & 127;
  int s = (idx >> 7) & 4095;
  int b = idx >> 19;
  float acc0 = 0, acc1 = 0, acc2 = 0, acc3 = 0, acc4 = 0, acc5 = 0, acc6 = 0, acc7 = 0;
  float den = 1e-6f;
  int nb = s >> 8, off = s & 255;
  if (nb <= 14) {
    uint4 u = *(const uint4*)(ow + ((size_t)(b * 15 + nb) * 512 + off) * 1024 + c8 * 8);
    acc0 += bf2f(u.x & 0xffff); acc1 += bf2f(u.x >> 16);
    acc2 += bf2f(u.y & 0xffff); acc3 += bf2f(u.y >> 16);
    acc4 += bf2f(u.z & 0xffff); acc5 += bf2f(u.z >> 16);
    acc6 += bf2f(u.w & 0xffff); acc7 += bf2f(u.w >> 16);
    den += 0.5f + off * (1.f / 511.f);
  }
  if (nb >= 1) {
    int off2 = off + 256;
    uint4 u = *(const uint4*)(ow + ((size_t)(b * 15 + nb - 1) * 512 + off2) * 1024 + c8 * 8);
    acc0 += bf2f(u.x & 0xffff); acc1 += bf2f(u.x >> 16);
    acc2 += bf2f(u.y & 0xffff); acc3 += bf2f(u.y >> 16);
    acc4 += bf2f(u.z & 0xffff); acc5 += bf2f(u.z >> 16);
    acc6 += bf2f(u.w & 0xffff); acc7 += bf2f(u.w >> 16);
    den += 0.5f + off2 * (1.f / 511.f);
  }
  float inv = 1.f / den;
  uint4 o;
  o.x = (u32)f2bf(acc0 * inv) | ((u32)f2bf(acc1 * inv) << 16);
  o.y = (u32)f2bf(acc2 * inv) | ((u32)f2bf(acc3 * inv) << 16);
  o.z = (u32)f2bf(acc4 * inv) | ((u32)f2bf(acc5 * inv) << 16);
  o.w = (u32)f2bf(acc6 * inv) | ((u32)f2bf(acc7 * inv) << 16);
  *(uint4*)(abf + ((size_t)(b * SEQ + s)) * 2048 + c8 * 8) = o;
}

// information broadcast: 2 channels/block, full S column in LDS, exact f32
__global__ __launch_bounds__(256) void k_bcast(const float* __restrict__ x,
                                               float* __restrict__ bc) {
  __shared__ float cur[2][4096];
  const int b = blockIdx.x >> 9;
  const int c0 = (blockIdx.x & 511) * 2;
  const int t = threadIdx.x;
  float cv[2][16], res[2][16];
#pragma unroll
  for (int j = 0; j < 16; ++j) {
    int r = t + 256 * j;
    float2 v = *(const float2*)&x[((size_t)b * SEQ + r) * HID + c0];
    cv[0][j] = v.x; cv[1][j] = v.y;
    cur[0][r] = v.x; cur[1][r] = v.y;
    res[0][j] = 0.f; res[1][j] = 0.f;
  }
  __syncthreads();
  for (int sh = 1; sh < 4096; sh <<= 1) {
    float nv[2][16];
#pragma unroll
    for (int j = 0; j < 16; ++j) {
      int r = t + 256 * j;
      int rm = (r - sh) & 4095, rp = (r + sh) & 4095;
      nv[0][j] = cv[0][j] + 0.5f * (cur[0][rm] + cur[0][rp]);
      nv[1][j] = cv[1][j] + 0.5f * (cur[1][rm] + cur[1][rp]);
    }
    __syncthreads();
#pragma unroll
    for (int j = 0; j < 16; ++j) {
      int r = t + 256 * j;
      cur[0][r] = nv[0][j]; cur[1][r] = nv[1][j];
      cv[0][j] = nv[0][j];  cv[1][j] = nv[1][j];
      res[0][j] += nv[0][j]; res[1][j] += nv[1][j];
    }
    __syncthreads();
  }
#pragma unroll
  for (int j = 0; j < 16; ++j) {
    int r = t + 256 * j;
    float2 o; o.x = res[0][j] * (1.f / 13.f); o.y = res[1][j] * (1.f / 13.f);
    *(float2*)&bc[((size_t)b * SEQ + r) * HID + c0] = o;
  }
}

// ---------------- launcher ----------------
extern "C" void kernel_launch(void* const* d_in, const int* in_sizes, int n_in,
                              void* d_out, int out_size, void* d_ws, size_t ws_size,
                              hipStream_t stream) {
  (void)in_sizes; (void)n_in; (void)out_size;
  const float* x      = (const float*)d_in[0];
  const float* gm     = (const float*)d_in[1];
  const float* conv_w = (const float*)d_in[2];
  const float* conv_b = (const float*)d_in[3];
  const float* mix_w  = (const float*)d_in[4];
  const float* mix_b  = (const float*)d_in[5];
  const float* out_w  = (const float*)d_in[6];
  const float* out_b  = (const float*)d_in[7];
  float* out = (float*)d_out;
  char* ws = (char*)d_ws;
  if (ws_size < 131596288ull) return;

  u16*   xbf     = (u16*)(ws + 0);             // 16 MB
  u16*   gtbf    = (u16*)(ws + 16777216);      // 0.5 MB
  u16*   XGbf    = (u16*)(ws + 17301504);      // 1 MB
  u16*   convWbf = (u16*)(ws + 18350080);      // 8 MB
  u16*   mixWT   = (u16*)(ws + 26738688);      // 4 MB
  u16*   outWT   = (u16*)(ws + 30932992);      // 2 MB
  u16*   ow      = (u16*)(ws + 33030144);      // 30 MB
  float* convpart= (float*)(ws + 33030144);    // 4 MB  (aliases ow; used before ow written)
  u16*   mixedbf = (u16*)(ws + 33030144);      // 16 MB (aliases ow; used after ow dead)
  u16*   Abf     = (u16*)(ws + 64487424);      // 32 MB
  float* bcast   = (float*)(ws + 98041856);    // 32 MB

  k_xbf<<<4096, 256, 0, stream>>>(x, xbf);
  k_transpose<<<512, 256, 0, stream>>>(mix_w, mixWT, 2048, 1024);
  k_transpose<<<256, 256, 0, stream>>>(out_w, outWT, 1024, 1024);
  k_cast4<<<4096, 256, 0, stream>>>(conv_w, convWbf);
  k_xg<<<128, 256, 0, stream>>>(x, XGbf);
  gemm_bt<0><<<64, 256, 0, stream>>>(XGbf, convWbf, 128, 1024, 512, 4096, 4096, 8,
                                     nullptr, convpart, nullptr, nullptr);
  k_gtfin<<<1024, 256, 0, stream>>>(convpart, gm, conv_b, gtbf);
  k_bcast<<<1024, 256, 0, stream>>>(x, bcast);
  k_attn_glob<<<1024, 256, 0, stream>>>(xbf, gtbf, Abf);
  k_attn_swa<<<1920, 256, 0, stream>>>(xbf, ow);
  k_combine<<<4096, 256, 0, stream>>>(ow, Abf);
  gemm_bt<1><<<512, 256, 0, stream>>>(Abf, mixWT, 8192, 1024, 2048, 2048, 2048, 8,
                                      mix_b, nullptr, mixedbf, bcast);
  gemm_bt<2><<<512, 256, 0, stream>>>(mixedbf, outWT, 8192, 1024, 1024, 1024, 1024, 8,
                                      out_b, out, nullptr, nullptr);
}

// Round 4
// 320.807 us; speedup vs baseline: 1.5330x; 1.1525x over previous
//
#include <hip/hip_runtime.h>
#include <hip/hip_bf16.h>
#include <cstdint>

#define NHEAD 16
#define WINL  512
#define STRW  256
#define BATCH 2
#define SEQ   4096
#define HID   1024

using bf16x8 = __attribute__((ext_vector_type(8))) short;
using f32x4  = __attribute__((ext_vector_type(4))) float;
typedef unsigned short u16;
typedef unsigned int   u32;

__device__ __forceinline__ u16 f2bf(float f) {
  u32 u = __builtin_bit_cast(u32, f);
  u += 0x7fffu + ((u >> 16) & 1u);           // RNE
  return (u16)(u >> 16);
}
__device__ __forceinline__ float bf2f(u16 s) {
  return __builtin_bit_cast(float, (u32)s << 16);
}
__device__ __forceinline__ void gload_lds16(const void* g, void* l) {
  __builtin_amdgcn_global_load_lds(
      (const __attribute__((address_space(1))) void*)g,
      (__attribute__((address_space(3))) void*)l, 16, 0, 0);
}

// ---------------- prep kernels ----------------
__global__ __launch_bounds__(256) void k_xbf(const float* __restrict__ x,
                                             u16* __restrict__ xb) {
  size_t i = (size_t)blockIdx.x * 256 + threadIdx.x;
  float4 f0 = ((const float4*)x)[2 * i];
  float4 f1 = ((const float4*)x)[2 * i + 1];
  uint4 o;
  o.x = (u32)f2bf(f0.x) | ((u32)f2bf(f0.y) << 16);
  o.y = (u32)f2bf(f0.z) | ((u32)f2bf(f0.w) << 16);
  o.z = (u32)f2bf(f1.x) | ((u32)f2bf(f1.y) << 16);
  o.w = (u32)f2bf(f1.z) | ((u32)f2bf(f1.w) << 16);
  ((uint4*)xb)[i] = o;
}

__global__ __launch_bounds__(256) void k_transpose(const float* __restrict__ W,
                                                   u16* __restrict__ WT, int K, int N) {
  __shared__ u16 t[64][72];
  const int nk = K >> 6;
  const int tk = blockIdx.x % nk, tn = blockIdx.x / nk;
  const int tid = threadIdx.x;
  const int lr = tid >> 4, lc = tid & 15;
#pragma unroll
  for (int rr = 0; rr < 4; ++rr) {
    int row = lr + rr * 16;
    float4 f = *(const float4*)&W[(size_t)(tk * 64 + row) * N + tn * 64 + lc * 4];
    t[row][lc * 4 + 0] = f2bf(f.x);
    t[row][lc * 4 + 1] = f2bf(f.y);
    t[row][lc * 4 + 2] = f2bf(f.z);
    t[row][lc * 4 + 3] = f2bf(f.w);
  }
  __syncthreads();
  const int orow = tid >> 2, oq = tid & 3;
  u32 pk[8];
#pragma unroll
  for (int j = 0; j < 8; ++j) {
    u16 a = t[oq * 16 + 2 * j][orow];
    u16 b = t[oq * 16 + 2 * j + 1][orow];
    pk[j] = (u32)a | ((u32)b << 16);
  }
  uint4 o0; o0.x = pk[0]; o0.y = pk[1]; o0.z = pk[2]; o0.w = pk[3];
  uint4 o1; o1.x = pk[4]; o1.y = pk[5]; o1.z = pk[6]; o1.w = pk[7];
  size_t base = (size_t)(tn * 64 + orow) * K + tk * 64 + oq * 16;
  *(uint4*)&WT[base] = o0;
  *(uint4*)&WT[base + 8] = o1;
}

__global__ __launch_bounds__(256) void k_cast4(const float* __restrict__ W,
                                               u16* __restrict__ Wb) {
  int i = blockIdx.x * 256 + threadIdx.x;
  float4 f = ((const float4*)W)[i];
  ushort4 u; u.x = f2bf(f.x); u.y = f2bf(f.y); u.z = f2bf(f.z); u.w = f2bf(f.w);
  ((ushort4*)Wb)[i] = u;
}

__global__ __launch_bounds__(256) void k_xg(const float* __restrict__ x,
                                            u16* __restrict__ XG) {
  int bg = blockIdx.x, b = bg >> 6, g = bg & 63;
  int rr = threadIdx.x >> 6, f4 = threadIdx.x & 63;
  const float* src = x + ((size_t)(b * SEQ + g * 4 + rr)) * HID;
  u16* dst = XG + (size_t)bg * 4096;
#pragma unroll
  for (int rep = 0; rep < 4; ++rep) {
    int c4 = rep * 64 + f4;
    float4 f = *(const float4*)&src[c4 * 4];
    dst[(c4 * 4 + 0) * 4 + rr] = f2bf(f.x);
    dst[(c4 * 4 + 1) * 4 + rr] = f2bf(f.y);
    dst[(c4 * 4 + 2) * 4 + rr] = f2bf(f.z);
    dst[(c4 * 4 + 3) * 4 + rr] = f2bf(f.w);
  }
}

__global__ __launch_bounds__(256) void k_gtfin(const float* __restrict__ part,
                                               const float* __restrict__ gm,
                                               const float* __restrict__ cb,
                                               u16* __restrict__ gtbf) {
  int i = blockIdx.x * 256 + threadIdx.x;
  int col = i & 1023, row = (i >> 10) & 127, b = i >> 17;
  float v;
  if (row < 64) {
    v = cb[col];
#pragma unroll
    for (int kc = 0; kc < 8; ++kc)
      v += part[(size_t)kc * 131072 + (size_t)(b * 64 + row) * 1024 + col];
  } else {
    int g = row - 64;
    v = gm[((size_t)(col >> 6) * 64 + g) * 64 + (col & 63)];
  }
  gtbf[(size_t)(b * 128 + row) * 1024 + col] = f2bf(v);
}

// ---------------- 128x128 bf16 MFMA GEMM, B^T layout, swizzled LDS ----------------
template <int EPI>
__global__ __launch_bounds__(256) void gemm_bt(
    const u16* __restrict__ A, const u16* __restrict__ Bt,
    int M, int N, int kext, int lda, int ldb, int nbn,
    const float* __restrict__ bias, float* __restrict__ outf,
    u16* __restrict__ outbf, const float* __restrict__ bcast) {
  __shared__ __align__(16) u16 As[128 * 64];
  __shared__ __align__(16) u16 Bs[128 * 64];
  const int nwg = gridDim.x;
  int id = blockIdx.x;
  id = (id & 7) * (nwg >> 3) + (id >> 3);        // XCD swizzle (nwg % 8 == 0)
  const int nbm = M >> 7;
  const int per = nbm * nbn;
  const int kc = id / per;
  int rem = id % per;
  const int bm = rem / nbn, bn = rem % nbn;
  const int tid = threadIdx.x;
  const int lane = tid & 63, wid = tid >> 6;
  const int wm = wid >> 1, wn = wid & 1;
  const int l15 = lane & 15, l4 = lane >> 4;
  f32x4 acc[4][4] = {};
  const int srow = tid >> 3, cg = tid & 7;
  const u16* gA = A + (size_t)(bm * 128) * lda + (size_t)kc * kext;
  const u16* gB = Bt + (size_t)(bn * 128) * ldb + (size_t)kc * kext;

  for (int k0 = 0; k0 < kext; k0 += 64) {
#pragma unroll
    for (int r4 = 0; r4 < 4; ++r4) {
      int row = srow + 32 * r4;
      int sc = ((cg ^ (row & 7)) << 3);
      gload_lds16(gA + (size_t)row * lda + k0 + sc, &As[row * 64 + cg * 8]);
      gload_lds16(gB + (size_t)row * ldb + k0 + sc, &Bs[row * 64 + cg * 8]);
    }
    __syncthreads();
#pragma unroll
    for (int ks = 0; ks < 2; ++ks) {
      bf16x8 af[4], bv[4];
#pragma unroll
      for (int m = 0; m < 4; ++m) {
        int row = wm * 64 + m * 16 + l15;
        af[m] = *(const bf16x8*)&As[row * 64 + (((ks * 4 + l4) ^ (row & 7)) << 3)];
      }
#pragma unroll
      for (int n = 0; n < 4; ++n) {
        int row = wn * 64 + n * 16 + l15;
        bv[n] = *(const bf16x8*)&Bs[row * 64 + (((ks * 4 + l4) ^ (row & 7)) << 3)];
      }
#pragma unroll
      for (int m = 0; m < 4; ++m)
#pragma unroll
        for (int n = 0; n < 4; ++n)
          acc[m][n] = __builtin_amdgcn_mfma_f32_16x16x32_bf16(af[m], bv[n], acc[m][n], 0, 0, 0);
    }
    __syncthreads();
  }

  const int row0 = bm * 128 + wm * 64, col0 = bn * 128 + wn * 64;
#pragma unroll
  for (int m = 0; m < 4; ++m)
#pragma unroll
    for (int n = 0; n < 4; ++n)
#pragma unroll
      for (int r = 0; r < 4; ++r) {
        int row = row0 + m * 16 + l4 * 4 + r;
        int col = col0 + n * 16 + l15;
        float v = acc[m][n][r];
        if (EPI == 0) {
          outf[(size_t)kc * M * N + (size_t)row * N + col] = v;
        } else if (EPI == 1) {
          float gate = 1.f / (1.f + __expf(-(v + bias[col])));
          float lv = bf2f(A[(size_t)row * lda + col]);
          float gv = bf2f(A[(size_t)row * lda + 1024 + col]);
          float mx = gate * lv + (1.f - gate) * gv + bcast[(size_t)row * HID + col];
          outbf[(size_t)row * HID + col] = f2bf(mx);
        } else {
          outf[(size_t)row * N + col] = v + bias[col];
        }
      }
}

// ---------------- flash attention, swapped-operand QK^T, LDS P^T staging ----------------
// Swapped QK: sv[nf][r] = S^T[k = nf*16 + l4*4 + r][q = l15]  (q lane-local).
// P^T staged per-wave in ps[q=16][k=64] (granule-XOR swizzled), read back as the
// PV B-operand (8 contiguous k per lane). PV: mfma(A=V^T, B=P^T) -> O^T[d][q].

__global__ __launch_bounds__(256) void k_attn_swa(const u16* __restrict__ xbf,
                                                  u16* __restrict__ ow) {
  __shared__ __align__(16) u16 kts[64 * 64];     // K chunk, granule-swizzled
  __shared__ __align__(16) u16 vsT[64 * 72];     // V^T [d][k], pad 72
  __shared__ __align__(16) u16 ps[4 * 1024];     // per-wave P^T [q=16][k=64], swizzled
  const int blk = blockIdx.x;
  const int b = blk / 960;
  int rem = blk % 960;
  const int n = rem / 64;  rem &= 63;
  const int h = rem >> 2, qc = rem & 3;
  const int tid = threadIdx.x, lane = tid & 63, wid = tid >> 6;
  const int l15 = lane & 15, l4 = lane >> 4;
  const int q0 = n * STRW + qc * 128;

  bf16x8 qf[2][2];   // Q[q = l15-local][d = ks*32 + l4*8 + j]
  {
    const u16* xq = xbf + ((size_t)(b * SEQ + q0 + wid * 32 + l15)) * HID + h * 64 + l4 * 8;
#pragma unroll
    for (int m = 0; m < 2; ++m)
#pragma unroll
      for (int ks = 0; ks < 2; ++ks)
        qf[m][ks] = *(const bf16x8*)(xq + (size_t)m * 16 * HID + ks * 32);
  }
  const int prow0 = wid * 16 + (lane >> 3);
  const int cg = lane & 7;
  const int vr = tid & 63, vdc = (tid >> 6) * 16;
  u16* psw = &ps[wid * 1024];

  float m_run[2], l_run[2];
  f32x4 Oc[2][4] = {};
#pragma unroll
  for (int m = 0; m < 2; ++m) { m_run[m] = -1e30f; l_run[m] = 0.f; }

  for (int c = 0; c < 8; ++c) {
    const int kb = n * STRW + c * 64;
    __syncthreads();
#pragma unroll
    for (int e = 0; e < 2; ++e) {    // K: global_load_lds, pre-swizzled source
      int row = prow0 + e * 8;
      const u16* src = xbf + ((size_t)(b * SEQ + kb + row)) * HID + h * 64 + ((cg ^ (row & 7)) << 3);
      gload_lds16(src, &kts[(wid * 2 + e) * 512 + lane * 8]);
    }
    {                                // V: register transpose -> vsT[d][k]
      const u16* vs = xbf + ((size_t)(b * SEQ + kb + vr)) * HID + h * 64 + vdc;
      uint4 v0 = *(const uint4*)vs;
      uint4 v1 = *(const uint4*)(vs + 8);
      u32 w_[8] = {v0.x, v0.y, v0.z, v0.w, v1.x, v1.y, v1.z, v1.w};
#pragma unroll
      for (int j = 0; j < 8; ++j) {
        vsT[(vdc + 2 * j) * 72 + vr] = (u16)w_[j];
        vsT[(vdc + 2 * j + 1) * 72 + vr] = (u16)(w_[j] >> 16);
      }
    }
    __syncthreads();

#pragma unroll
    for (int m = 0; m < 2; ++m) {
      // QK^T swapped: sv[nf][r] = S^T[k = nf*16 + l4*4 + r][q = l15]
      float sv[4][4];
#pragma unroll
      for (int nf = 0; nf < 4; ++nf) {
        f32x4 s = {};
#pragma unroll
        for (int ks = 0; ks < 2; ++ks) {
          int krow = nf * 16 + l15;
          bf16x8 ka = *(const bf16x8*)&kts[krow * 64 + (((ks * 4 + l4) ^ (krow & 7)) << 3)];
          s = __builtin_amdgcn_mfma_f32_16x16x32_bf16(ka, qf[m][ks], s, 0, 0, 0);
        }
#pragma unroll
        for (int r = 0; r < 4; ++r) sv[nf][r] = s[r] * 0.125f;
      }
      // per-q max: 16 in-lane + combine 4 l4-groups
      float mx = sv[0][0];
#pragma unroll
      for (int nf = 0; nf < 4; ++nf)
#pragma unroll
        for (int r = 0; r < 4; ++r) mx = fmaxf(mx, sv[nf][r]);
      mx = fmaxf(mx, __shfl_xor(mx, 16, 64));
      mx = fmaxf(mx, __shfl_xor(mx, 32, 64));
      float mnew = fmaxf(m_run[m], mx);
      float alpha = __expf(m_run[m] - mnew);
      m_run[m] = mnew;
      float rs = 0.f;
#pragma unroll
      for (int nf = 0; nf < 4; ++nf)
#pragma unroll
        for (int r = 0; r < 4; ++r) {
          float p = __expf(sv[nf][r] - mnew);
          sv[nf][r] = p; rs += p;
        }
      rs += __shfl_xor(rs, 16, 64);
      rs += __shfl_xor(rs, 32, 64);
      l_run[m] = l_run[m] * alpha + rs;
#pragma unroll
      for (int nf = 0; nf < 4; ++nf)
#pragma unroll
        for (int r = 0; r < 4; ++r) Oc[m][nf][r] *= alpha;

      // stage P^T: ps[q = l15][k = nf*16 + l4*4 + r], XOR-swizzled 8-u16 granules
#pragma unroll
      for (int nf = 0; nf < 4; ++nf) {
        uint2 pr;
        pr.x = (u32)f2bf(sv[nf][0]) | ((u32)f2bf(sv[nf][1]) << 16);
        pr.y = (u32)f2bf(sv[nf][2]) | ((u32)f2bf(sv[nf][3]) << 16);
        int g = (nf * 2 + (l4 >> 1)) ^ (l15 & 7);
        *(uint2*)&psw[l15 * 64 + g * 8 + (l4 & 1) * 4] = pr;
      }
      asm volatile("s_waitcnt lgkmcnt(0)" ::: "memory");
      __builtin_amdgcn_sched_barrier(0);
      bf16x8 pb[2];   // P^T[k = ks2*32 + l4*8 + j][q = l15]
#pragma unroll
      for (int ks2 = 0; ks2 < 2; ++ks2)
        pb[ks2] = *(const bf16x8*)&psw[l15 * 64 + (((ks2 * 4 + l4) ^ (l15 & 7)) << 3)];

      // PV: O^T[d][q] += V^T[d][k] * P^T[k][q]
#pragma unroll
      for (int nf = 0; nf < 4; ++nf) {
        f32x4 o = Oc[m][nf];
#pragma unroll
        for (int ks2 = 0; ks2 < 2; ++ks2) {
          bf16x8 va = *(const bf16x8*)&vsT[(nf * 16 + l15) * 72 + ks2 * 32 + l4 * 8];
          o = __builtin_amdgcn_mfma_f32_16x16x32_bf16(va, pb[ks2], o, 0, 0, 0);
        }
        Oc[m][nf] = o;
      }
    }
  }
#pragma unroll
  for (int m = 0; m < 2; ++m) {
    int qoff = qc * 128 + wid * 32 + m * 16 + l15;
    float tri = 0.5f + (float)qoff * (1.0f / 511.0f);
    float sc = tri / l_run[m];
    u16* dst = ow + ((size_t)(b * 15 + n) * 512 + qoff) * 1024 + h * 64 + l4 * 4;
#pragma unroll
    for (int nf = 0; nf < 4; ++nf) {
      ushort4 o4;
      o4.x = f2bf(Oc[m][nf][0] * sc); o4.y = f2bf(Oc[m][nf][1] * sc);
      o4.z = f2bf(Oc[m][nf][2] * sc); o4.w = f2bf(Oc[m][nf][3] * sc);
      *(ushort4*)(dst + nf * 16) = o4;
    }
  }
}

__global__ __launch_bounds__(256) void k_attn_glob(const u16* __restrict__ xbf,
                                                   const u16* __restrict__ gtbf,
                                                   u16* __restrict__ abf) {
  __shared__ __align__(16) u16 kts[64 * 64];
  __shared__ __align__(16) u16 vsT[64 * 72];
  __shared__ __align__(16) u16 ps[4 * 1024];
  const int blk = blockIdx.x;
  const int b = blk >> 9, h = (blk >> 5) & 15, qc = blk & 31;
  const int tid = threadIdx.x, lane = tid & 63, wid = tid >> 6;
  const int l15 = lane & 15, l4 = lane >> 4;
  const int q0 = qc * 128;
  bf16x8 qf[2][2];
  {
    const u16* xq = xbf + ((size_t)(b * SEQ + q0 + wid * 32 + l15)) * HID + h * 64 + l4 * 8;
#pragma unroll
    for (int m = 0; m < 2; ++m)
#pragma unroll
      for (int ks = 0; ks < 2; ++ks)
        qf[m][ks] = *(const bf16x8*)(xq + (size_t)m * 16 * HID + ks * 32);
  }
  const int prow0 = wid * 16 + (lane >> 3);
  const int cg = lane & 7;
  const int vr = tid & 63, vdc = (tid >> 6) * 16;
  u16* psw = &ps[wid * 1024];

  float m_run[2], l_run[2];
  f32x4 Oc[2][4] = {};
#pragma unroll
  for (int m = 0; m < 2; ++m) { m_run[m] = -1e30f; l_run[m] = 0.f; }

  for (int c = 0; c < 2; ++c) {
    const int kb = c * 64;
    __syncthreads();
#pragma unroll
    for (int e = 0; e < 2; ++e) {
      int row = prow0 + e * 8;
      const u16* src = gtbf + ((size_t)(b * 128 + kb + row)) * HID + h * 64 + ((cg ^ (row & 7)) << 3);
      gload_lds16(src, &kts[(wid * 2 + e) * 512 + lane * 8]);
    }
    {
      const u16* vs = gtbf + ((size_t)(b * 128 + kb + vr)) * HID + h * 64 + vdc;
      uint4 v0 = *(const uint4*)vs;
      uint4 v1 = *(const uint4*)(vs + 8);
      u32 w_[8] = {v0.x, v0.y, v0.z, v0.w, v1.x, v1.y, v1.z, v1.w};
#pragma unroll
      for (int j = 0; j < 8; ++j) {
        vsT[(vdc + 2 * j) * 72 + vr] = (u16)w_[j];
        vsT[(vdc + 2 * j + 1) * 72 + vr] = (u16)(w_[j] >> 16);
      }
    }
    __syncthreads();

#pragma unroll
    for (int m = 0; m < 2; ++m) {
      float sv[4][4];
#pragma unroll
      for (int nf = 0; nf < 4; ++nf) {
        f32x4 s = {};
#pragma unroll
        for (int ks = 0; ks < 2; ++ks) {
          int krow = nf * 16 + l15;
          bf16x8 ka = *(const bf16x8*)&kts[krow * 64 + (((ks * 4 + l4) ^ (krow & 7)) << 3)];
          s = __builtin_amdgcn_mfma_f32_16x16x32_bf16(ka, qf[m][ks], s, 0, 0, 0);
        }
#pragma unroll
        for (int r = 0; r < 4; ++r) sv[nf][r] = s[r] * 0.125f;
      }
      float mx = sv[0][0];
#pragma unroll
      for (int nf = 0; nf < 4; ++nf)
#pragma unroll
        for (int r = 0; r < 4; ++r) mx = fmaxf(mx, sv[nf][r]);
      mx = fmaxf(mx, __shfl_xor(mx, 16, 64));
      mx = fmaxf(mx, __shfl_xor(mx, 32, 64));
      float mnew = fmaxf(m_run[m], mx);
      float alpha = __expf(m_run[m] - mnew);
      m_run[m] = mnew;
      float rs = 0.f;
#pragma unroll
      for (int nf = 0; nf < 4; ++nf)
#pragma unroll
        for (int r = 0; r < 4; ++r) {
          float p = __expf(sv[nf][r] - mnew);
          sv[nf][r] = p; rs += p;
        }
      rs += __shfl_xor(rs, 16, 64);
      rs += __shfl_xor(rs, 32, 64);
      l_run[m] = l_run[m] * alpha + rs;
#pragma unroll
      for (int nf = 0; nf < 4; ++nf)
#pragma unroll
        for (int r = 0; r < 4; ++r) Oc[m][nf][r] *= alpha;

#pragma unroll
      for (int nf = 0; nf < 4; ++nf) {
        uint2 pr;
        pr.x = (u32)f2bf(sv[nf][0]) | ((u32)f2bf(sv[nf][1]) << 16);
        pr.y = (u32)f2bf(sv[nf][2]) | ((u32)f2bf(sv[nf][3]) << 16);
        int g = (nf * 2 + (l4 >> 1)) ^ (l15 & 7);
        *(uint2*)&psw[l15 * 64 + g * 8 + (l4 & 1) * 4] = pr;
      }
      asm volatile("s_waitcnt lgkmcnt(0)" ::: "memory");
      __builtin_amdgcn_sched_barrier(0);
      bf16x8 pb[2];
#pragma unroll
      for (int ks2 = 0; ks2 < 2; ++ks2)
        pb[ks2] = *(const bf16x8*)&psw[l15 * 64 + (((ks2 * 4 + l4) ^ (l15 & 7)) << 3)];

#pragma unroll
      for (int nf = 0; nf < 4; ++nf) {
        f32x4 o = Oc[m][nf];
#pragma unroll
        for (int ks2 = 0; ks2 < 2; ++ks2) {
          bf16x8 va = *(const bf16x8*)&vsT[(nf * 16 + l15) * 72 + ks2 * 32 + l4 * 8];
          o = __builtin_amdgcn_mfma_f32_16x16x32_bf16(va, pb[ks2], o, 0, 0, 0);
        }
        Oc[m][nf] = o;
      }
    }
  }
#pragma unroll
  for (int m = 0; m < 2; ++m) {
    int s = q0 + wid * 32 + m * 16 + l15;
    float sc = 1.f / l_run[m];
    u16* dst = abf + ((size_t)(b * SEQ + s)) * 2048 + 1024 + h * 64 + l4 * 4;
#pragma unroll
    for (int nf = 0; nf < 4; ++nf) {
      ushort4 o4;
      o4.x = f2bf(Oc[m][nf][0] * sc); o4.y = f2bf(Oc[m][nf][1] * sc);
      o4.z = f2bf(Oc[m][nf][2] * sc); o4.w = f2bf(Oc[m][nf][3] * sc);
      *(ushort4*)(dst + nf * 16) = o4;
    }
  }
}

// combine tri-weighted window outputs -> Abf cols 0..1023
__global__ __launch_bounds__(256) void k_combine(const u16* __restrict__ ow,
                                                 u16* __restrict__ abf) {
  int idx = blockIdx.x * 256 + threadIdx.x;
  int c8 = idx & 127;
  int s = (idx >> 7) & 4095;
  int b = idx >> 19;
  float acc0 = 0, acc1 = 0, acc2 = 0, acc3 = 0, acc4 = 0, acc5 = 0, acc6 = 0, acc7 = 0;
  float den = 1e-6f;
  int nb = s >> 8, off = s & 255;
  if (nb <= 14) {
    uint4 u = *(const uint4*)(ow + ((size_t)(b * 15 + nb) * 512 + off) * 1024 + c8 * 8);
    acc0 += bf2f(u.x & 0xffff); acc1 += bf2f(u.x >> 16);
    acc2 += bf2f(u.y & 0xffff); acc3 += bf2f(u.y >> 16);
    acc4 += bf2f(u.z & 0xffff); acc5 += bf2f(u.z >> 16);
    acc6 += bf2f(u.w & 0xffff); acc7 += bf2f(u.w >> 16);
    den += 0.5f + off * (1.f / 511.f);
  }
  if (nb >= 1) {
    int off2 = off + 256;
    uint4 u = *(const uint4*)(ow + ((size_t)(b * 15 + nb - 1) * 512 + off2) * 1024 + c8 * 8);
    acc0 += bf2f(u.x & 0xffff); acc1 += bf2f(u.x >> 16);
    acc2 += bf2f(u.y & 0xffff); acc3 += bf2f(u.y >> 16);
    acc4 += bf2f(u.z & 0xffff); acc5 += bf2f(u.z >> 16);
    acc6 += bf2f(u.w & 0xffff); acc7 += bf2f(u.w >> 16);
    den += 0.5f + off2 * (1.f / 511.f);
  }
  float inv = 1.f / den;
  uint4 o;
  o.x = (u32)f2bf(acc0 * inv) | ((u32)f2bf(acc1 * inv) << 16);
  o.y = (u32)f2bf(acc2 * inv) | ((u32)f2bf(acc3 * inv) << 16);
  o.z = (u32)f2bf(acc4 * inv) | ((u32)f2bf(acc5 * inv) << 16);
  o.w = (u32)f2bf(acc6 * inv) | ((u32)f2bf(acc7 * inv) << 16);
  *(uint4*)(abf + ((size_t)(b * SEQ + s)) * 2048 + c8 * 8) = o;
}

// information broadcast: 2 channels/block, full S column in LDS, exact f32
__global__ __launch_bounds__(256) void k_bcast(const float* __restrict__ x,
                                               float* __restrict__ bc) {
  __shared__ float cur[2][4096];
  const int b = blockIdx.x >> 9;
  const int c0 = (blockIdx.x & 511) * 2;
  const int t = threadIdx.x;
  float cv[2][16], res[2][16];
#pragma unroll
  for (int j = 0; j < 16; ++j) {
    int r = t + 256 * j;
    float2 v = *(const float2*)&x[((size_t)b * SEQ + r) * HID + c0];
    cv[0][j] = v.x; cv[1][j] = v.y;
    cur[0][r] = v.x; cur[1][r] = v.y;
    res[0][j] = 0.f; res[1][j] = 0.f;
  }
  __syncthreads();
  for (int sh = 1; sh < 4096; sh <<= 1) {
    float nv[2][16];
#pragma unroll
    for (int j = 0; j < 16; ++j) {
      int r = t + 256 * j;
      int rm = (r - sh) & 4095, rp = (r + sh) & 4095;
      nv[0][j] = cv[0][j] + 0.5f * (cur[0][rm] + cur[0][rp]);
      nv[1][j] = cv[1][j] + 0.5f * (cur[1][rm] + cur[1][rp]);
    }
    __syncthreads();
#pragma unroll
    for (int j = 0; j < 16; ++j) {
      int r = t + 256 * j;
      cur[0][r] = nv[0][j]; cur[1][r] = nv[1][j];
      cv[0][j] = nv[0][j];  cv[1][j] = nv[1][j];
      res[0][j] += nv[0][j]; res[1][j] += nv[1][j];
    }
    __syncthreads();
  }
#pragma unroll
  for (int j = 0; j < 16; ++j) {
    int r = t + 256 * j;
    float2 o; o.x = res[0][j] * (1.f / 13.f); o.y = res[1][j] * (1.f / 13.f);
    *(float2*)&bc[((size_t)b * SEQ + r) * HID + c0] = o;
  }
}

// ---------------- launcher ----------------
extern "C" void kernel_launch(void* const* d_in, const int* in_sizes, int n_in,
                              void* d_out, int out_size, void* d_ws, size_t ws_size,
                              hipStream_t stream) {
  (void)in_sizes; (void)n_in; (void)out_size;
  const float* x      = (const float*)d_in[0];
  const float* gm     = (const float*)d_in[1];
  const float* conv_w = (const float*)d_in[2];
  const float* conv_b = (const float*)d_in[3];
  const float* mix_w  = (const float*)d_in[4];
  const float* mix_b  = (const float*)d_in[5];
  const float* out_w  = (const float*)d_in[6];
  const float* out_b  = (const float*)d_in[7];
  float* out = (float*)d_out;
  char* ws = (char*)d_ws;
  if (ws_size < 131596288ull) return;

  u16*   xbf     = (u16*)(ws + 0);             // 16 MB
  u16*   gtbf    = (u16*)(ws + 16777216);      // 0.5 MB
  u16*   XGbf    = (u16*)(ws + 17301504);      // 1 MB
  u16*   convWbf = (u16*)(ws + 18350080);      // 8 MB
  u16*   mixWT   = (u16*)(ws + 26738688);      // 4 MB
  u16*   outWT   = (u16*)(ws + 30932992);      // 2 MB
  u16*   ow      = (u16*)(ws + 33030144);      // 30 MB
  float* convpart= (float*)(ws + 33030144);    // 4 MB  (aliases ow; used before ow written)
  u16*   mixedbf = (u16*)(ws + 33030144);      // 16 MB (aliases ow; used after ow dead)
  u16*   Abf     = (u16*)(ws + 64487424);      // 32 MB
  float* bcast   = (float*)(ws + 98041856);    // 32 MB

  k_xbf<<<4096, 256, 0, stream>>>(x, xbf);
  k_transpose<<<512, 256, 0, stream>>>(mix_w, mixWT, 2048, 1024);
  k_transpose<<<256, 256, 0, stream>>>(out_w, outWT, 1024, 1024);
  k_cast4<<<4096, 256, 0, stream>>>(conv_w, convWbf);
  k_xg<<<128, 256, 0, stream>>>(x, XGbf);
  gemm_bt<0><<<64, 256, 0, stream>>>(XGbf, convWbf, 128, 1024, 512, 4096, 4096, 8,
                                     nullptr, convpart, nullptr, nullptr);
  k_gtfin<<<1024, 256, 0, stream>>>(convpart, gm, conv_b, gtbf);
  k_bcast<<<1024, 256, 0, stream>>>(x, bcast);
  k_attn_glob<<<1024, 256, 0, stream>>>(xbf, gtbf, Abf);
  k_attn_swa<<<1920, 256, 0, stream>>>(xbf, ow);
  k_combine<<<4096, 256, 0, stream>>>(ow, Abf);
  gemm_bt<1><<<512, 256, 0, stream>>>(Abf, mixWT, 8192, 1024, 2048, 2048, 2048, 8,
                                      mix_b, nullptr, mixedbf, bcast);
  gemm_bt<2><<<512, 256, 0, stream>>>(mixedbf, outWT, 8192, 1024, 1024, 1024, 1024, 8,
                                      out_b, out, nullptr, nullptr);
}

// Round 5
// 268.919 us; speedup vs baseline: 1.8288x; 1.1930x over previous
//
#include <hip/hip_runtime.h>
#include <hip/hip_bf16.h>
#include <cstdint>

#define NHEAD 16
#define WINL  512
#define STRW  256
#define BATCH 2
#define SEQ   4096
#define HID   1024

using bf16x8 = __attribute__((ext_vector_type(8))) short;
using f32x4  = __attribute__((ext_vector_type(4))) float;
typedef unsigned short u16;
typedef unsigned int   u32;

__device__ __forceinline__ u16 f2bf(float f) {
  u32 u = __builtin_bit_cast(u32, f);
  u += 0x7fffu + ((u >> 16) & 1u);           // RNE
  return (u16)(u >> 16);
}
__device__ __forceinline__ float bf2f(u16 s) {
  return __builtin_bit_cast(float, (u32)s << 16);
}
__device__ __forceinline__ void gload_lds16(const void* g, void* l) {
  __builtin_amdgcn_global_load_lds(
      (const __attribute__((address_space(1))) void*)g,
      (__attribute__((address_space(3))) void*)l, 16, 0, 0);
}

// ---------------- prep kernels ----------------
// 64x64 tile: x f32 -> xbf (bf16, same layout) + xT (f32, [B*H][S] transposed)
// grid 2048 = 128 row-tiles x 16 col-tiles
__global__ __launch_bounds__(256) void k_xbfT(const float* __restrict__ x,
                                              u16* __restrict__ xb,
                                              float* __restrict__ xT) {
  __shared__ float t[64][65];
  const int tr = blockIdx.x >> 4, tc = blockIdx.x & 15;
  const int r0 = tr * 64, c0 = tc * 64;
  const int lr = threadIdx.x >> 4, lc4 = (threadIdx.x & 15) * 4;
#pragma unroll
  for (int rr = 0; rr < 4; ++rr) {
    int row = lr + rr * 16;
    float4 f = *(const float4*)&x[(size_t)(r0 + row) * HID + c0 + lc4];
    uint2 o;
    o.x = (u32)f2bf(f.x) | ((u32)f2bf(f.y) << 16);
    o.y = (u32)f2bf(f.z) | ((u32)f2bf(f.w) << 16);
    *(uint2*)&xb[(size_t)(r0 + row) * HID + c0 + lc4] = o;
    t[row][lc4 + 0] = f.x; t[row][lc4 + 1] = f.y;
    t[row][lc4 + 2] = f.z; t[row][lc4 + 3] = f.w;
  }
  __syncthreads();
  const int b = r0 >> 12, s0 = r0 & 4095;
#pragma unroll
  for (int rr = 0; rr < 4; ++rr) {
    int cl = lr + rr * 16;
    float4 o;
    o.x = t[lc4 + 0][cl]; o.y = t[lc4 + 1][cl];
    o.z = t[lc4 + 2][cl]; o.w = t[lc4 + 3][cl];
    *(float4*)&xT[((size_t)(b * HID + c0 + cl)) * SEQ + s0 + lc4] = o;
  }
}

__global__ __launch_bounds__(256) void k_transpose(const float* __restrict__ W,
                                                   u16* __restrict__ WT, int K, int N) {
  __shared__ u16 t[64][72];
  const int nk = K >> 6;
  const int tk = blockIdx.x % nk, tn = blockIdx.x / nk;
  const int tid = threadIdx.x;
  const int lr = tid >> 4, lc = tid & 15;
#pragma unroll
  for (int rr = 0; rr < 4; ++rr) {
    int row = lr + rr * 16;
    float4 f = *(const float4*)&W[(size_t)(tk * 64 + row) * N + tn * 64 + lc * 4];
    t[row][lc * 4 + 0] = f2bf(f.x);
    t[row][lc * 4 + 1] = f2bf(f.y);
    t[row][lc * 4 + 2] = f2bf(f.z);
    t[row][lc * 4 + 3] = f2bf(f.w);
  }
  __syncthreads();
  const int orow = tid >> 2, oq = tid & 3;
  u32 pk[8];
#pragma unroll
  for (int j = 0; j < 8; ++j) {
    u16 a = t[oq * 16 + 2 * j][orow];
    u16 b = t[oq * 16 + 2 * j + 1][orow];
    pk[j] = (u32)a | ((u32)b << 16);
  }
  uint4 o0; o0.x = pk[0]; o0.y = pk[1]; o0.z = pk[2]; o0.w = pk[3];
  uint4 o1; o1.x = pk[4]; o1.y = pk[5]; o1.z = pk[6]; o1.w = pk[7];
  size_t base = (size_t)(tn * 64 + orow) * K + tk * 64 + oq * 16;
  *(uint4*)&WT[base] = o0;
  *(uint4*)&WT[base + 8] = o1;
}

__global__ __launch_bounds__(256) void k_cast4(const float* __restrict__ W,
                                               u16* __restrict__ Wb) {
  int i = blockIdx.x * 256 + threadIdx.x;
  float4 f = ((const float4*)W)[i];
  ushort4 u; u.x = f2bf(f.x); u.y = f2bf(f.y); u.z = f2bf(f.z); u.w = f2bf(f.w);
  ((ushort4*)Wb)[i] = u;
}

__global__ __launch_bounds__(256) void k_xg(const float* __restrict__ x,
                                            u16* __restrict__ XG) {
  int bg = blockIdx.x, b = bg >> 6, g = bg & 63;
  int rr = threadIdx.x >> 6, f4 = threadIdx.x & 63;
  const float* src = x + ((size_t)(b * SEQ + g * 4 + rr)) * HID;
  u16* dst = XG + (size_t)bg * 4096;
#pragma unroll
  for (int rep = 0; rep < 4; ++rep) {
    int c4 = rep * 64 + f4;
    float4 f = *(const float4*)&src[c4 * 4];
    dst[(c4 * 4 + 0) * 4 + rr] = f2bf(f.x);
    dst[(c4 * 4 + 1) * 4 + rr] = f2bf(f.y);
    dst[(c4 * 4 + 2) * 4 + rr] = f2bf(f.z);
    dst[(c4 * 4 + 3) * 4 + rr] = f2bf(f.w);
  }
}

__global__ __launch_bounds__(256) void k_gtfin(const float* __restrict__ part,
                                               const float* __restrict__ gm,
                                               const float* __restrict__ cb,
                                               u16* __restrict__ gtbf) {
  int i = blockIdx.x * 256 + threadIdx.x;
  int col = i & 1023, row = (i >> 10) & 127, b = i >> 17;
  float v;
  if (row < 64) {
    v = cb[col];
#pragma unroll
    for (int kc = 0; kc < 8; ++kc)
      v += part[(size_t)kc * 131072 + (size_t)(b * 64 + row) * 1024 + col];
  } else {
    int g = row - 64;
    v = gm[((size_t)(col >> 6) * 64 + g) * 64 + (col & 63)];
  }
  gtbf[(size_t)(b * 128 + row) * 1024 + col] = f2bf(v);
}

// ---------------- 128x128 bf16 MFMA GEMM, B^T layout, swizzled LDS ----------------
template <int EPI>
__global__ __launch_bounds__(256) void gemm_bt(
    const u16* __restrict__ A, const u16* __restrict__ Bt,
    int M, int N, int kext, int lda, int ldb, int nbn,
    const float* __restrict__ bias, float* __restrict__ outf,
    u16* __restrict__ outbf, const float* __restrict__ bcast) {
  __shared__ __align__(16) u16 As[128 * 64];
  __shared__ __align__(16) u16 Bs[128 * 64];
  const int nwg = gridDim.x;
  int id = blockIdx.x;
  id = (id & 7) * (nwg >> 3) + (id >> 3);        // XCD swizzle (nwg % 8 == 0)
  const int nbm = M >> 7;
  const int per = nbm * nbn;
  const int kc = id / per;
  int rem = id % per;
  const int bm = rem / nbn, bn = rem % nbn;
  const int tid = threadIdx.x;
  const int lane = tid & 63, wid = tid >> 6;
  const int wm = wid >> 1, wn = wid & 1;
  const int l15 = lane & 15, l4 = lane >> 4;
  f32x4 acc[4][4] = {};
  const int srow = tid >> 3, cg = tid & 7;
  const u16* gA = A + (size_t)(bm * 128) * lda + (size_t)kc * kext;
  const u16* gB = Bt + (size_t)(bn * 128) * ldb + (size_t)kc * kext;

  for (int k0 = 0; k0 < kext; k0 += 64) {
#pragma unroll
    for (int r4 = 0; r4 < 4; ++r4) {
      int row = srow + 32 * r4;
      int sc = ((cg ^ (row & 7)) << 3);
      gload_lds16(gA + (size_t)row * lda + k0 + sc, &As[row * 64 + cg * 8]);
      gload_lds16(gB + (size_t)row * ldb + k0 + sc, &Bs[row * 64 + cg * 8]);
    }
    __syncthreads();
#pragma unroll
    for (int ks = 0; ks < 2; ++ks) {
      bf16x8 af[4], bv[4];
#pragma unroll
      for (int m = 0; m < 4; ++m) {
        int row = wm * 64 + m * 16 + l15;
        af[m] = *(const bf16x8*)&As[row * 64 + (((ks * 4 + l4) ^ (row & 7)) << 3)];
      }
#pragma unroll
      for (int n = 0; n < 4; ++n) {
        int row = wn * 64 + n * 16 + l15;
        bv[n] = *(const bf16x8*)&Bs[row * 64 + (((ks * 4 + l4) ^ (row & 7)) << 3)];
      }
#pragma unroll
      for (int m = 0; m < 4; ++m)
#pragma unroll
        for (int n = 0; n < 4; ++n)
          acc[m][n] = __builtin_amdgcn_mfma_f32_16x16x32_bf16(af[m], bv[n], acc[m][n], 0, 0, 0);
    }
    __syncthreads();
  }

  const int row0 = bm * 128 + wm * 64, col0 = bn * 128 + wn * 64;
#pragma unroll
  for (int m = 0; m < 4; ++m)
#pragma unroll
    for (int n = 0; n < 4; ++n)
#pragma unroll
      for (int r = 0; r < 4; ++r) {
        int row = row0 + m * 16 + l4 * 4 + r;
        int col = col0 + n * 16 + l15;
        float v = acc[m][n][r];
        if (EPI == 0) {
          outf[(size_t)kc * M * N + (size_t)row * N + col] = v;
        } else if (EPI == 1) {
          float gate = 1.f / (1.f + __expf(-(v + bias[col])));
          float lv = bf2f(A[(size_t)row * lda + col]);
          float gv = bf2f(A[(size_t)row * lda + 1024 + col]);
          float mx = gate * lv + (1.f - gate) * gv + bcast[(size_t)row * HID + col];
          outbf[(size_t)row * HID + col] = f2bf(mx);
        } else {
          outf[(size_t)row * N + col] = v + bias[col];
        }
      }
}

// ---------------- flash attention, swapped-operand QK^T, LDS P^T staging ----------------
__global__ __launch_bounds__(256) void k_attn_swa(const u16* __restrict__ xbf,
                                                  u16* __restrict__ ow) {
  __shared__ __align__(16) u16 kts[64 * 64];     // K chunk, granule-swizzled
  __shared__ __align__(16) u16 vsT[64 * 72];     // V^T [d][k], pad 72
  __shared__ __align__(16) u16 ps[4 * 1024];     // per-wave P^T [q=16][k=64], swizzled
  const int blk = blockIdx.x;
  const int b = blk / 960;
  int rem = blk % 960;
  const int n = rem / 64;  rem &= 63;
  const int h = rem >> 2, qc = rem & 3;
  const int tid = threadIdx.x, lane = tid & 63, wid = tid >> 6;
  const int l15 = lane & 15, l4 = lane >> 4;
  const int q0 = n * STRW + qc * 128;

  bf16x8 qf[2][2];   // Q[q = l15-local][d = ks*32 + l4*8 + j]
  {
    const u16* xq = xbf + ((size_t)(b * SEQ + q0 + wid * 32 + l15)) * HID + h * 64 + l4 * 8;
#pragma unroll
    for (int m = 0; m < 2; ++m)
#pragma unroll
      for (int ks = 0; ks < 2; ++ks)
        qf[m][ks] = *(const bf16x8*)(xq + (size_t)m * 16 * HID + ks * 32);
  }
  const int prow0 = wid * 16 + (lane >> 3);
  const int cg = lane & 7;
  const int vr = tid & 63, vdc = (tid >> 6) * 16;
  u16* psw = &ps[wid * 1024];

  float m_run[2], l_run[2];
  f32x4 Oc[2][4] = {};
#pragma unroll
  for (int m = 0; m < 2; ++m) { m_run[m] = -1e30f; l_run[m] = 0.f; }

  for (int c = 0; c < 8; ++c) {
    const int kb = n * STRW + c * 64;
    __syncthreads();
#pragma unroll
    for (int e = 0; e < 2; ++e) {    // K: global_load_lds, pre-swizzled source
      int row = prow0 + e * 8;
      const u16* src = xbf + ((size_t)(b * SEQ + kb + row)) * HID + h * 64 + ((cg ^ (row & 7)) << 3);
      gload_lds16(src, &kts[(wid * 2 + e) * 512 + lane * 8]);
    }
    {                                // V: register transpose -> vsT[d][k]
      const u16* vs = xbf + ((size_t)(b * SEQ + kb + vr)) * HID + h * 64 + vdc;
      uint4 v0 = *(const uint4*)vs;
      uint4 v1 = *(const uint4*)(vs + 8);
      u32 w_[8] = {v0.x, v0.y, v0.z, v0.w, v1.x, v1.y, v1.z, v1.w};
#pragma unroll
      for (int j = 0; j < 8; ++j) {
        vsT[(vdc + 2 * j) * 72 + vr] = (u16)w_[j];
        vsT[(vdc + 2 * j + 1) * 72 + vr] = (u16)(w_[j] >> 16);
      }
    }
    __syncthreads();

#pragma unroll
    for (int m = 0; m < 2; ++m) {
      // QK^T swapped: sv[nf][r] = S^T[k = nf*16 + l4*4 + r][q = l15]
      float sv[4][4];
#pragma unroll
      for (int nf = 0; nf < 4; ++nf) {
        f32x4 s = {};
#pragma unroll
        for (int ks = 0; ks < 2; ++ks) {
          int krow = nf * 16 + l15;
          bf16x8 ka = *(const bf16x8*)&kts[krow * 64 + (((ks * 4 + l4) ^ (krow & 7)) << 3)];
          s = __builtin_amdgcn_mfma_f32_16x16x32_bf16(ka, qf[m][ks], s, 0, 0, 0);
        }
#pragma unroll
        for (int r = 0; r < 4; ++r) sv[nf][r] = s[r] * 0.125f;
      }
      float mx = sv[0][0];
#pragma unroll
      for (int nf = 0; nf < 4; ++nf)
#pragma unroll
        for (int r = 0; r < 4; ++r) mx = fmaxf(mx, sv[nf][r]);
      mx = fmaxf(mx, __shfl_xor(mx, 16, 64));
      mx = fmaxf(mx, __shfl_xor(mx, 32, 64));
      float mnew = fmaxf(m_run[m], mx);
      float alpha = __expf(m_run[m] - mnew);
      m_run[m] = mnew;
      float rs = 0.f;
#pragma unroll
      for (int nf = 0; nf < 4; ++nf)
#pragma unroll
        for (int r = 0; r < 4; ++r) {
          float p = __expf(sv[nf][r] - mnew);
          sv[nf][r] = p; rs += p;
        }
      rs += __shfl_xor(rs, 16, 64);
      rs += __shfl_xor(rs, 32, 64);
      l_run[m] = l_run[m] * alpha + rs;
#pragma unroll
      for (int nf = 0; nf < 4; ++nf)
#pragma unroll
        for (int r = 0; r < 4; ++r) Oc[m][nf][r] *= alpha;

      // stage P^T: ps[q = l15][k = nf*16 + l4*4 + r], XOR-swizzled 8-u16 granules
#pragma unroll
      for (int nf = 0; nf < 4; ++nf) {
        uint2 pr;
        pr.x = (u32)f2bf(sv[nf][0]) | ((u32)f2bf(sv[nf][1]) << 16);
        pr.y = (u32)f2bf(sv[nf][2]) | ((u32)f2bf(sv[nf][3]) << 16);
        int g = (nf * 2 + (l4 >> 1)) ^ (l15 & 7);
        *(uint2*)&psw[l15 * 64 + g * 8 + (l4 & 1) * 4] = pr;
      }
      asm volatile("s_waitcnt lgkmcnt(0)" ::: "memory");
      __builtin_amdgcn_sched_barrier(0);
      bf16x8 pb[2];   // P^T[k = ks2*32 + l4*8 + j][q = l15]
#pragma unroll
      for (int ks2 = 0; ks2 < 2; ++ks2)
        pb[ks2] = *(const bf16x8*)&psw[l15 * 64 + (((ks2 * 4 + l4) ^ (l15 & 7)) << 3)];

      // PV: O^T[d][q] += V^T[d][k] * P^T[k][q]
#pragma unroll
      for (int nf = 0; nf < 4; ++nf) {
        f32x4 o = Oc[m][nf];
#pragma unroll
        for (int ks2 = 0; ks2 < 2; ++ks2) {
          bf16x8 va = *(const bf16x8*)&vsT[(nf * 16 + l15) * 72 + ks2 * 32 + l4 * 8];
          o = __builtin_amdgcn_mfma_f32_16x16x32_bf16(va, pb[ks2], o, 0, 0, 0);
        }
        Oc[m][nf] = o;
      }
    }
  }
#pragma unroll
  for (int m = 0; m < 2; ++m) {
    int qoff = qc * 128 + wid * 32 + m * 16 + l15;
    float tri = 0.5f + (float)qoff * (1.0f / 511.0f);
    float sc = tri / l_run[m];
    u16* dst = ow + ((size_t)(b * 15 + n) * 512 + qoff) * 1024 + h * 64 + l4 * 4;
#pragma unroll
    for (int nf = 0; nf < 4; ++nf) {
      ushort4 o4;
      o4.x = f2bf(Oc[m][nf][0] * sc); o4.y = f2bf(Oc[m][nf][1] * sc);
      o4.z = f2bf(Oc[m][nf][2] * sc); o4.w = f2bf(Oc[m][nf][3] * sc);
      *(ushort4*)(dst + nf * 16) = o4;
    }
  }
}

__global__ __launch_bounds__(256) void k_attn_glob(const u16* __restrict__ xbf,
                                                   const u16* __restrict__ gtbf,
                                                   u16* __restrict__ abf) {
  __shared__ __align__(16) u16 kts[64 * 64];
  __shared__ __align__(16) u16 vsT[64 * 72];
  __shared__ __align__(16) u16 ps[4 * 1024];
  const int blk = blockIdx.x;
  const int b = blk >> 9, h = (blk >> 5) & 15, qc = blk & 31;
  const int tid = threadIdx.x, lane = tid & 63, wid = tid >> 6;
  const int l15 = lane & 15, l4 = lane >> 4;
  const int q0 = qc * 128;
  bf16x8 qf[2][2];
  {
    const u16* xq = xbf + ((size_t)(b * SEQ + q0 + wid * 32 + l15)) * HID + h * 64 + l4 * 8;
#pragma unroll
    for (int m = 0; m < 2; ++m)
#pragma unroll
      for (int ks = 0; ks < 2; ++ks)
        qf[m][ks] = *(const bf16x8*)(xq + (size_t)m * 16 * HID + ks * 32);
  }
  const int prow0 = wid * 16 + (lane >> 3);
  const int cg = lane & 7;
  const int vr = tid & 63, vdc = (tid >> 6) * 16;
  u16* psw = &ps[wid * 1024];

  float m_run[2], l_run[2];
  f32x4 Oc[2][4] = {};
#pragma unroll
  for (int m = 0; m < 2; ++m) { m_run[m] = -1e30f; l_run[m] = 0.f; }

  for (int c = 0; c < 2; ++c) {
    const int kb = c * 64;
    __syncthreads();
#pragma unroll
    for (int e = 0; e < 2; ++e) {
      int row = prow0 + e * 8;
      const u16* src = gtbf + ((size_t)(b * 128 + kb + row)) * HID + h * 64 + ((cg ^ (row & 7)) << 3);
      gload_lds16(src, &kts[(wid * 2 + e) * 512 + lane * 8]);
    }
    {
      const u16* vs = gtbf + ((size_t)(b * 128 + kb + vr)) * HID + h * 64 + vdc;
      uint4 v0 = *(const uint4*)vs;
      uint4 v1 = *(const uint4*)(vs + 8);
      u32 w_[8] = {v0.x, v0.y, v0.z, v0.w, v1.x, v1.y, v1.z, v1.w};
#pragma unroll
      for (int j = 0; j < 8; ++j) {
        vsT[(vdc + 2 * j) * 72 + vr] = (u16)w_[j];
        vsT[(vdc + 2 * j + 1) * 72 + vr] = (u16)(w_[j] >> 16);
      }
    }
    __syncthreads();

#pragma unroll
    for (int m = 0; m < 2; ++m) {
      float sv[4][4];
#pragma unroll
      for (int nf = 0; nf < 4; ++nf) {
        f32x4 s = {};
#pragma unroll
        for (int ks = 0; ks < 2; ++ks) {
          int krow = nf * 16 + l15;
          bf16x8 ka = *(const bf16x8*)&kts[krow * 64 + (((ks * 4 + l4) ^ (krow & 7)) << 3)];
          s = __builtin_amdgcn_mfma_f32_16x16x32_bf16(ka, qf[m][ks], s, 0, 0, 0);
        }
#pragma unroll
        for (int r = 0; r < 4; ++r) sv[nf][r] = s[r] * 0.125f;
      }
      float mx = sv[0][0];
#pragma unroll
      for (int nf = 0; nf < 4; ++nf)
#pragma unroll
        for (int r = 0; r < 4; ++r) mx = fmaxf(mx, sv[nf][r]);
      mx = fmaxf(mx, __shfl_xor(mx, 16, 64));
      mx = fmaxf(mx, __shfl_xor(mx, 32, 64));
      float mnew = fmaxf(m_run[m], mx);
      float alpha = __expf(m_run[m] - mnew);
      m_run[m] = mnew;
      float rs = 0.f;
#pragma unroll
      for (int nf = 0; nf < 4; ++nf)
#pragma unroll
        for (int r = 0; r < 4; ++r) {
          float p = __expf(sv[nf][r] - mnew);
          sv[nf][r] = p; rs += p;
        }
      rs += __shfl_xor(rs, 16, 64);
      rs += __shfl_xor(rs, 32, 64);
      l_run[m] = l_run[m] * alpha + rs;
#pragma unroll
      for (int nf = 0; nf < 4; ++nf)
#pragma unroll
        for (int r = 0; r < 4; ++r) Oc[m][nf][r] *= alpha;

#pragma unroll
      for (int nf = 0; nf < 4; ++nf) {
        uint2 pr;
        pr.x = (u32)f2bf(sv[nf][0]) | ((u32)f2bf(sv[nf][1]) << 16);
        pr.y = (u32)f2bf(sv[nf][2]) | ((u32)f2bf(sv[nf][3]) << 16);
        int g = (nf * 2 + (l4 >> 1)) ^ (l15 & 7);
        *(uint2*)&psw[l15 * 64 + g * 8 + (l4 & 1) * 4] = pr;
      }
      asm volatile("s_waitcnt lgkmcnt(0)" ::: "memory");
      __builtin_amdgcn_sched_barrier(0);
      bf16x8 pb[2];
#pragma unroll
      for (int ks2 = 0; ks2 < 2; ++ks2)
        pb[ks2] = *(const bf16x8*)&psw[l15 * 64 + (((ks2 * 4 + l4) ^ (l15 & 7)) << 3)];

#pragma unroll
      for (int nf = 0; nf < 4; ++nf) {
        f32x4 o = Oc[m][nf];
#pragma unroll
        for (int ks2 = 0; ks2 < 2; ++ks2) {
          bf16x8 va = *(const bf16x8*)&vsT[(nf * 16 + l15) * 72 + ks2 * 32 + l4 * 8];
          o = __builtin_amdgcn_mfma_f32_16x16x32_bf16(va, pb[ks2], o, 0, 0, 0);
        }
        Oc[m][nf] = o;
      }
    }
  }
#pragma unroll
  for (int m = 0; m < 2; ++m) {
    int s = q0 + wid * 32 + m * 16 + l15;
    float sc = 1.f / l_run[m];
    u16* dst = abf + ((size_t)(b * SEQ + s)) * 2048 + 1024 + h * 64 + l4 * 4;
#pragma unroll
    for (int nf = 0; nf < 4; ++nf) {
      ushort4 o4;
      o4.x = f2bf(Oc[m][nf][0] * sc); o4.y = f2bf(Oc[m][nf][1] * sc);
      o4.z = f2bf(Oc[m][nf][2] * sc); o4.w = f2bf(Oc[m][nf][3] * sc);
      *(ushort4*)(dst + nf * 16) = o4;
    }
  }
}

// combine tri-weighted window outputs -> Abf cols 0..1023
__global__ __launch_bounds__(256) void k_combine(const u16* __restrict__ ow,
                                                 u16* __restrict__ abf) {
  int idx = blockIdx.x * 256 + threadIdx.x;
  int c8 = idx & 127;
  int s = (idx >> 7) & 4095;
  int b = idx >> 19;
  float acc0 = 0, acc1 = 0, acc2 = 0, acc3 = 0, acc4 = 0, acc5 = 0, acc6 = 0, acc7 = 0;
  float den = 1e-6f;
  int nb = s >> 8, off = s & 255;
  if (nb <= 14) {
    uint4 u = *(const uint4*)(ow + ((size_t)(b * 15 + nb) * 512 + off) * 1024 + c8 * 8);
    acc0 += bf2f(u.x & 0xffff); acc1 += bf2f(u.x >> 16);
    acc2 += bf2f(u.y & 0xffff); acc3 += bf2f(u.y >> 16);
    acc4 += bf2f(u.z & 0xffff); acc5 += bf2f(u.z >> 16);
    acc6 += bf2f(u.w & 0xffff); acc7 += bf2f(u.w >> 16);
    den += 0.5f + off * (1.f / 511.f);
  }
  if (nb >= 1) {
    int off2 = off + 256;
    uint4 u = *(const uint4*)(ow + ((size_t)(b * 15 + nb - 1) * 512 + off2) * 1024 + c8 * 8);
    acc0 += bf2f(u.x & 0xffff); acc1 += bf2f(u.x >> 16);
    acc2 += bf2f(u.y & 0xffff); acc3 += bf2f(u.y >> 16);
    acc4 += bf2f(u.z & 0xffff); acc5 += bf2f(u.z >> 16);
    acc6 += bf2f(u.w & 0xffff); acc7 += bf2f(u.w >> 16);
    den += 0.5f + off2 * (1.f / 511.f);
  }
  float inv = 1.f / den;
  uint4 o;
  o.x = (u32)f2bf(acc0 * inv) | ((u32)f2bf(acc1 * inv) << 16);
  o.y = (u32)f2bf(acc2 * inv) | ((u32)f2bf(acc3 * inv) << 16);
  o.z = (u32)f2bf(acc4 * inv) | ((u32)f2bf(acc5 * inv) << 16);
  o.w = (u32)f2bf(acc6 * inv) | ((u32)f2bf(acc7 * inv) << 16);
  *(uint4*)(abf + ((size_t)(b * SEQ + s)) * 2048 + c8 * 8) = o;
}

// information broadcast on transposed layout: block = 2 channel-rows of xT [2048][4096]
// fully coalesced stride-1 global access; same exact-f32 math as before
__global__ __launch_bounds__(256) void k_bcast2(const float* __restrict__ xT,
                                                float* __restrict__ bcT) {
  __shared__ float cur[2][4096];
  const int cr = blockIdx.x * 2;
  const float* s0 = xT + (size_t)cr * 4096;
  const float* s1 = xT + (size_t)(cr + 1) * 4096;
  const int t = threadIdx.x;
  float cv[2][16], res[2][16];
#pragma unroll
  for (int j = 0; j < 16; ++j) {
    int r = t + 256 * j;
    float v0 = s0[r], v1 = s1[r];
    cv[0][j] = v0; cv[1][j] = v1;
    cur[0][r] = v0; cur[1][r] = v1;
    res[0][j] = 0.f; res[1][j] = 0.f;
  }
  __syncthreads();
  for (int sh = 1; sh < 4096; sh <<= 1) {
    float nv[2][16];
#pragma unroll
    for (int j = 0; j < 16; ++j) {
      int r = t + 256 * j;
      int rm = (r - sh) & 4095, rp = (r + sh) & 4095;
      nv[0][j] = cv[0][j] + 0.5f * (cur[0][rm] + cur[0][rp]);
      nv[1][j] = cv[1][j] + 0.5f * (cur[1][rm] + cur[1][rp]);
    }
    __syncthreads();
#pragma unroll
    for (int j = 0; j < 16; ++j) {
      int r = t + 256 * j;
      cur[0][r] = nv[0][j]; cur[1][r] = nv[1][j];
      cv[0][j] = nv[0][j];  cv[1][j] = nv[1][j];
      res[0][j] += nv[0][j]; res[1][j] += nv[1][j];
    }
    __syncthreads();
  }
#pragma unroll
  for (int j = 0; j < 16; ++j) {
    int r = t + 256 * j;
    bcT[(size_t)cr * 4096 + r] = res[0][j] * (1.f / 13.f);
    bcT[(size_t)(cr + 1) * 4096 + r] = res[1][j] * (1.f / 13.f);
  }
}

// transpose back: bcT [B*H][S] -> bc [B*S][H]; 64x64 f32 tiles, coalesced both ways
// grid 2048 = 32 channel-tiles x 64 s-tiles
__global__ __launch_bounds__(256) void k_tback(const float* __restrict__ bcT,
                                               float* __restrict__ bc) {
  __shared__ float t[64][65];
  const int tcr = blockIdx.x >> 6, ts = blockIdx.x & 63;
  const int cr0 = tcr * 64, s0 = ts * 64;
  const int lr = threadIdx.x >> 4, lc4 = (threadIdx.x & 15) * 4;
#pragma unroll
  for (int rr = 0; rr < 4; ++rr) {
    int row = lr + rr * 16;
    float4 f = *(const float4*)&bcT[(size_t)(cr0 + row) * 4096 + s0 + lc4];
    t[row][lc4 + 0] = f.x; t[row][lc4 + 1] = f.y;
    t[row][lc4 + 2] = f.z; t[row][lc4 + 3] = f.w;
  }
  __syncthreads();
  const int b = cr0 >> 10, c0 = cr0 & 1023;
#pragma unroll
  for (int rr = 0; rr < 4; ++rr) {
    int srow = lr + rr * 16;
    float4 o;
    o.x = t[lc4 + 0][srow]; o.y = t[lc4 + 1][srow];
    o.z = t[lc4 + 2][srow]; o.w = t[lc4 + 3][srow];
    *(float4*)&bc[((size_t)(b * SEQ + s0 + srow)) * HID + c0 + lc4] = o;
  }
}

// ---------------- launcher ----------------
extern "C" void kernel_launch(void* const* d_in, const int* in_sizes, int n_in,
                              void* d_out, int out_size, void* d_ws, size_t ws_size,
                              hipStream_t stream) {
  (void)in_sizes; (void)n_in; (void)out_size;
  const float* x      = (const float*)d_in[0];
  const float* gm     = (const float*)d_in[1];
  const float* conv_w = (const float*)d_in[2];
  const float* conv_b = (const float*)d_in[3];
  const float* mix_w  = (const float*)d_in[4];
  const float* mix_b  = (const float*)d_in[5];
  const float* out_w  = (const float*)d_in[6];
  const float* out_b  = (const float*)d_in[7];
  float* out = (float*)d_out;
  char* ws = (char*)d_ws;
  if (ws_size < 131596288ull) return;

  const size_t MB = 1048576ull;
  u16*   xbf     = (u16*)(ws + 0);               // 16 MB   [live: all]
  u16*   mixWT   = (u16*)(ws + 16 * MB);         //  4 MB
  u16*   outWT   = (u16*)(ws + 20 * MB);         //  2 MB
  u16*   gtbf    = (u16*)(ws + 22 * MB);         //  0.5 MB
  char*  slotA   = ws + 23 * MB;                 // 32 MB: xT (early) then Abf
  float* xT      = (float*)slotA;
  u16*   Abf     = (u16*)slotA;
  char*  slotB   = ws + 55 * MB;                 // 32 MB: convWbf/XGbf/convpart -> bcastT -> ow -> mixedbf
  u16*   convWbf = (u16*)slotB;                  //  8 MB
  u16*   XGbf    = (u16*)(slotB + 8 * MB);       //  1 MB
  float* convpart= (float*)(slotB + 9 * MB);     //  4 MB
  float* bcastT  = (float*)slotB;                // 32 MB
  u16*   ow      = (u16*)slotB;                  // 30 MB
  u16*   mixedbf = (u16*)slotB;                  // 16 MB
  float* bcast   = (float*)(ws + 87 * MB);       // 32 MB  [ends at 119 MB]

  k_xbfT<<<2048, 256, 0, stream>>>(x, xbf, xT);
  k_transpose<<<512, 256, 0, stream>>>(mix_w, mixWT, 2048, 1024);
  k_transpose<<<256, 256, 0, stream>>>(out_w, outWT, 1024, 1024);
  k_cast4<<<4096, 256, 0, stream>>>(conv_w, convWbf);
  k_xg<<<128, 256, 0, stream>>>(x, XGbf);
  gemm_bt<0><<<64, 256, 0, stream>>>(XGbf, convWbf, 128, 1024, 512, 4096, 4096, 8,
                                     nullptr, convpart, nullptr, nullptr);
  k_gtfin<<<1024, 256, 0, stream>>>(convpart, gm, conv_b, gtbf);
  k_bcast2<<<1024, 256, 0, stream>>>(xT, bcastT);     // xT dead after this
  k_tback<<<2048, 256, 0, stream>>>(bcastT, bcast);   // bcastT dead after this
  k_attn_glob<<<1024, 256, 0, stream>>>(xbf, gtbf, Abf);
  k_attn_swa<<<1920, 256, 0, stream>>>(xbf, ow);
  k_combine<<<4096, 256, 0, stream>>>(ow, Abf);       // ow dead after this
  gemm_bt<1><<<512, 256, 0, stream>>>(Abf, mixWT, 8192, 1024, 2048, 2048, 2048, 8,
                                      mix_b, nullptr, mixedbf, bcast);
  gemm_bt<2><<<512, 256, 0, stream>>>(mixedbf, outWT, 8192, 1024, 1024, 1024, 1024, 8,
                                      out_b, out, nullptr, nullptr);
}